// Round 9
// baseline (310.709 us; speedup 1.0000x reference)
//
#include <hip/hip_runtime.h>
#include <hip/hip_bf16.h>

#define N_NODES 100000
#define N_EDGES 600000
#define HIDDEN 128
#define N_LAYERS 4
#define MPAD 100096   // N_NODES rounded up to 128 (and to 64)

#define TAP0_BLOCKS ((N_NODES * 16) / 256)                       // 6250
#define CNT_BLOCKS ((N_EDGES + 255) / 256)                       // 2344
#define PREPW_BLOCKS ((N_LAYERS * HIDDEN * HIDDEN + 255) / 256)  // 256

typedef short bf16x8 __attribute__((ext_vector_type(8)));
typedef float f32x4 __attribute__((ext_vector_type(4)));
typedef float f32x8 __attribute__((ext_vector_type(8)));

__device__ inline ushort f2bf(float f) {
    __hip_bfloat16 h = __float2bfloat16(f);
    return *reinterpret_cast<ushort*>(&h);
}

__device__ inline float bfhi(uint u) { return __uint_as_float(u << 16); }
__device__ inline float bflo(uint u) { return __uint_as_float(u & 0xffff0000u); }

// ===========================================================================
// Prologue (fused independent prep): tap0+cast x0 | count_dst | prep_w
// tap0: 16 lanes per node, f32x8 per lane -> 4-step shfl reduce (round-8
// lesson: 1-node/wave + 6-step shfl chain was latency-bound at 1.5 TB/s).
// ===========================================================================
__global__ void prologue(const float* __restrict__ x, const float* __restrict__ We,
                         const float* __restrict__ be, const float* __restrict__ temp,
                         float* __restrict__ energy, uint* __restrict__ xb,
                         const int* __restrict__ dst, int* __restrict__ cnt,
                         const float* __restrict__ Ws, ushort* __restrict__ whi,
                         ushort* __restrict__ wlo) {
    int b = blockIdx.x;
    if (b < TAP0_BLOCKS) {
        int gtid = b * 256 + threadIdx.x;
        int n = gtid >> 4, l16 = gtid & 15;
        f32x8 v = *(const f32x8*)(x + (size_t)n * HIDDEN + l16 * 8);
        uint4 packed;
        packed.x = (uint)f2bf(v[0]) | ((uint)f2bf(v[1]) << 16);
        packed.y = (uint)f2bf(v[2]) | ((uint)f2bf(v[3]) << 16);
        packed.z = (uint)f2bf(v[4]) | ((uint)f2bf(v[5]) << 16);
        packed.w = (uint)f2bf(v[6]) | ((uint)f2bf(v[7]) << 16);
        ((uint4*)(xb + (size_t)n * 64))[l16] = packed;
        f32x8 we = *(const f32x8*)(We + l16 * 8);
        float dot = v[0] * we[0] + v[1] * we[1] + v[2] * we[2] + v[3] * we[3]
                  + v[4] * we[4] + v[5] * we[5] + v[6] * we[6] + v[7] * we[7];
        #pragma unroll
        for (int off = 8; off > 0; off >>= 1) dot += __shfl_xor(dot, off);
        if (l16 == 0) energy[n] = (dot + be[0]) * temp[0];
    } else if (b < TAP0_BLOCKS + CNT_BLOCKS) {
        int e = (b - TAP0_BLOCKS) * 256 + threadIdx.x;
        if (e < N_EDGES) atomicAdd(&cnt[dst[e]], 1);
    } else {
        int idx = (b - TAP0_BLOCKS - CNT_BLOCKS) * 256 + threadIdx.x;
        if (idx < N_LAYERS * HIDDEN * HIDDEN) {
            int l = idx >> 14;
            int r = idx & 16383;
            int c = r >> 7, k = r & 127;
            float v = Ws[(l << 14) + k * HIDDEN + c];
            ushort hi = f2bf(v);
            float hif = __uint_as_float(((uint)hi) << 16);
            whi[idx] = hi;
            wlo[idx] = f2bf(v - hif);
        }
    }
}

// ===========================================================================
// Exclusive scan (3 passes) over cnt -> rowptr
// ===========================================================================
__global__ void scan1(const int* __restrict__ cnt, int* __restrict__ excl,
                      int* __restrict__ bsums, int n) {
    __shared__ int lds[8];
    int t = threadIdx.x;
    int base = blockIdx.x * 1024 + t * 4;
    int v0 = (base + 0 < n) ? cnt[base + 0] : 0;
    int v1 = (base + 1 < n) ? cnt[base + 1] : 0;
    int v2 = (base + 2 < n) ? cnt[base + 2] : 0;
    int v3 = (base + 3 < n) ? cnt[base + 3] : 0;
    int tsum = v0 + v1 + v2 + v3;
    int lane = t & 63, wv = t >> 6;
    int s = tsum;
    #pragma unroll
    for (int off = 1; off < 64; off <<= 1) {
        int u = __shfl_up(s, off);
        if (lane >= off) s += u;
    }
    if (lane == 63) lds[wv] = s;
    __syncthreads();
    if (t == 0) {
        int a = 0;
        #pragma unroll
        for (int i = 0; i < 4; ++i) { int bb = lds[i]; lds[i] = a; a += bb; }
        lds[4] = a;
    }
    __syncthreads();
    int excl_t = (s - tsum) + lds[wv];
    if (base + 0 < n) excl[base + 0] = excl_t;
    if (base + 1 < n) excl[base + 1] = excl_t + v0;
    if (base + 2 < n) excl[base + 2] = excl_t + v0 + v1;
    if (base + 3 < n) excl[base + 3] = excl_t + v0 + v1 + v2;
    if (t == 0) bsums[blockIdx.x] = lds[4];
}

__global__ void scan2(int* __restrict__ bsums, int nb) {
    __shared__ int wsum[4];
    int t = threadIdx.x;
    int v = (t < nb) ? bsums[t] : 0;
    int lane = t & 63, wv = t >> 6;
    int s = v;
    #pragma unroll
    for (int off = 1; off < 64; off <<= 1) {
        int u = __shfl_up(s, off);
        if (lane >= off) s += u;
    }
    if (lane == 63) wsum[wv] = s;
    __syncthreads();
    int add = 0;
    for (int i = 0; i < wv; ++i) add += wsum[i];
    if (t < nb) bsums[t] = (s - v) + add;
}

__global__ void scan3(const int* __restrict__ excl, const int* __restrict__ bsums,
                      int* __restrict__ rowptr, int n) {
    int i = blockIdx.x * blockDim.x + threadIdx.x;
    if (i < n) rowptr[i] = excl[i] + bsums[i >> 10];
    else if (i == n) rowptr[n] = N_EDGES;
}

__global__ void fill_csr(const int* __restrict__ src, const int* __restrict__ dst,
                         const float* __restrict__ w, const int* __restrict__ rowptr,
                         int* __restrict__ fillc, int2* __restrict__ epack) {
    int e = blockIdx.x * blockDim.x + threadIdx.x;
    if (e >= N_EDGES) return;
    int d = dst[e];
    int pos = atomicAdd(&fillc[d], 1);
    int slot = rowptr[d] + pos;
    epack[slot] = make_int2(src[e], __float_as_int(w[e]));
}

// ===========================================================================
// LDS-staged MFMA GEMM: x plain bf16, W split (2 products Whi*x + Wlo*x).
// Block: 256 thr / 4 waves; tile = 64 nodes x 128 cols; LDS 16 KB,
// XOR-swizzled (col16B ^= (row&7)) -> conflict-free ds_read_b128.
// ===========================================================================
__global__ __launch_bounds__(256) void gemm_lds(
    const uint* __restrict__ xb,
    const ushort* __restrict__ whi, const ushort* __restrict__ wlo,
    const float* __restrict__ b, ushort* __restrict__ h) {
    __shared__ uint4 sx4[1024];          // 16 KB
    char* sxb = (char*)sx4;
    int t = threadIdx.x;
    int lane = t & 63, wv = t >> 6;
    int l15 = lane & 15, l4 = lane >> 4;
    int row0 = blockIdx.x * 64;
    int c0 = wv * 32;

    // A fragments (W side), global (L1-hot), hoisted before staging
    bf16x8 Ah[2][4], Al[2][4];
    #pragma unroll
    for (int m = 0; m < 2; ++m) {
        int c = c0 + m * 16 + l15;
        #pragma unroll
        for (int s = 0; s < 4; ++s) {
            int off = c * HIDDEN + s * 32 + l4 * 8;
            Ah[m][s] = *(const bf16x8*)(whi + off);
            Al[m][s] = *(const bf16x8*)(wlo + off);
        }
    }

    // Stage x tile: 1024 16B-chunks; thread t takes chunks j*256+t
    #pragma unroll
    for (int j = 0; j < 4; ++j) {
        int c = j * 256 + t;          // chunk index in [0,1024)
        int row = c >> 4;             // 0..63
        int colb = (c & 15) * 16;     // byte col 0..255
        int grow = row0 + row;
        if (grow >= N_NODES) grow = N_NODES - 1;
        uint4 v = *(const uint4*)((const char*)xb + (size_t)grow * 256 + colb);
        *(uint4*)(sxb + row * 256 + (colb ^ ((row & 7) << 4))) = v;
    }
    __syncthreads();

    f32x4 acc[2][4];
    #pragma unroll
    for (int m = 0; m < 2; ++m)
        #pragma unroll
        for (int n = 0; n < 4; ++n)
            acc[m][n] = f32x4{0.f, 0.f, 0.f, 0.f};

    #pragma unroll
    for (int n = 0; n < 4; ++n) {
        int row = n * 16 + l15;
        int rsw = (row & 7) << 4;
        #pragma unroll
        for (int s = 0; s < 4; ++s) {
            bf16x8 bh = *(const bf16x8*)(sxb + row * 256 + ((s * 64 + l4 * 16) ^ rsw));
            #pragma unroll
            for (int m = 0; m < 2; ++m) {
                acc[m][n] = __builtin_amdgcn_mfma_f32_16x16x32_bf16(Ah[m][s], bh, acc[m][n], 0, 0, 0);
                acc[m][n] = __builtin_amdgcn_mfma_f32_16x16x32_bf16(Al[m][s], bh, acc[m][n], 0, 0, 0);
            }
        }
    }

    // Epilogue: +bias, pack bf16, store (h padded to MPAD rows, unguarded)
    #pragma unroll
    for (int m = 0; m < 2; ++m) {
        f32x4 bias = *(const f32x4*)(b + c0 + m * 16 + l4 * 4);
        #pragma unroll
        for (int n = 0; n < 4; ++n) {
            int node = row0 + n * 16 + l15;
            f32x4 r = acc[m][n] + bias;
            uint2 packed;
            packed.x = (uint)f2bf(r[0]) | ((uint)f2bf(r[1]) << 16);
            packed.y = (uint)f2bf(r[2]) | ((uint)f2bf(r[3]) << 16);
            *(uint2*)(h + (size_t)node * HIDDEN + c0 + m * 16 + l4 * 4) = packed;
        }
    }
}

// ===========================================================================
// Fused CSR aggregation + leaky-relu + energy tap.
// 16 lanes per node, uint4 per lane. Static exact-width tiers; deg>=8 issues
// 8 gathers in ONE basic block (8 in flight); no padded 256B requests.
// LAST=0: write bf16 x (uint4, coalesced). LAST=1: write f32 x to d_out.
// ===========================================================================
#define LOADE(P, J) int2 P = epack[J]
#define GATH(U, P) uint4 U = *(const uint4*)(hrow + (size_t)P.x * 256 + cb)
#define FMA8(U, P) { float wk = __int_as_float(P.y); \
    a0 += bfhi(U.x) * wk; a1 += bflo(U.x) * wk; \
    a2 += bfhi(U.y) * wk; a3 += bflo(U.y) * wk; \
    a4 += bfhi(U.z) * wk; a5 += bflo(U.z) * wk; \
    a6 += bfhi(U.w) * wk; a7 += bflo(U.w) * wk; }

template <int LAST>
__global__ void agg_relu_tap(const ushort* __restrict__ h, const int* __restrict__ rowptr,
                             const int2* __restrict__ epack,
                             const float* __restrict__ We_l, const float* __restrict__ be_l,
                             const float* __restrict__ temp_l,
                             uint* __restrict__ xb, float* __restrict__ xout,
                             float* __restrict__ energy) {
    int gtid = blockIdx.x * blockDim.x + threadIdx.x;
    int n = gtid >> 4;          // one 16-lane group per node
    int l16 = gtid & 15;
    if (n >= N_NODES) return;
    int j0 = rowptr[n], j1 = rowptr[n + 1];
    int deg = j1 - j0;

    float a0 = 0.f, a1 = 0.f, a2 = 0.f, a3 = 0.f;
    float a4 = 0.f, a5 = 0.f, a6 = 0.f, a7 = 0.f;
    const char* hrow = (const char*)h;
    int cb = l16 * 16;          // byte offset of this lane's 16B chunk

    if (deg >= 8) {
        LOADE(p0, j0 + 0); LOADE(p1, j0 + 1); LOADE(p2, j0 + 2); LOADE(p3, j0 + 3);
        LOADE(p4, j0 + 4); LOADE(p5, j0 + 5); LOADE(p6, j0 + 6); LOADE(p7, j0 + 7);
        GATH(u0, p0); GATH(u1, p1); GATH(u2, p2); GATH(u3, p3);
        GATH(u4, p4); GATH(u5, p5); GATH(u6, p6); GATH(u7, p7);
        FMA8(u0, p0); FMA8(u1, p1); FMA8(u2, p2); FMA8(u3, p3);
        FMA8(u4, p4); FMA8(u5, p5); FMA8(u6, p6); FMA8(u7, p7);
        int j = j0 + 8;
        for (; j + 4 <= j1; j += 4) {
            LOADE(q0, j + 0); LOADE(q1, j + 1); LOADE(q2, j + 2); LOADE(q3, j + 3);
            GATH(v0, q0); GATH(v1, q1); GATH(v2, q2); GATH(v3, q3);
            FMA8(v0, q0); FMA8(v1, q1); FMA8(v2, q2); FMA8(v3, q3);
        }
        if (j + 2 <= j1) {
            LOADE(q0, j + 0); LOADE(q1, j + 1);
            GATH(v0, q0); GATH(v1, q1);
            FMA8(v0, q0); FMA8(v1, q1);
            j += 2;
        }
        if (j < j1) { LOADE(q0, j); GATH(v0, q0); FMA8(v0, q0); }
    } else if (deg >= 4) {
        LOADE(p0, j0 + 0); LOADE(p1, j0 + 1); LOADE(p2, j0 + 2); LOADE(p3, j0 + 3);
        GATH(u0, p0); GATH(u1, p1); GATH(u2, p2); GATH(u3, p3);
        FMA8(u0, p0); FMA8(u1, p1); FMA8(u2, p2); FMA8(u3, p3);
        if (deg >= 6) {
            LOADE(q0, j0 + 4); LOADE(q1, j0 + 5);
            GATH(v0, q0); GATH(v1, q1);
            FMA8(v0, q0); FMA8(v1, q1);
        }
        if (deg & 1) { LOADE(q0, j1 - 1); GATH(v0, q0); FMA8(v0, q0); }
    } else if (deg > 0) {
        if (deg >= 2) {
            LOADE(p0, j0 + 0); LOADE(p1, j0 + 1);
            GATH(u0, p0); GATH(u1, p1);
            FMA8(u0, p0); FMA8(u1, p1);
        }
        if (deg & 1) { LOADE(q0, j1 - 1); GATH(v0, q0); FMA8(v0, q0); }
    }

    a0 = a0 > 0.f ? a0 : 0.01f * a0;
    a1 = a1 > 0.f ? a1 : 0.01f * a1;
    a2 = a2 > 0.f ? a2 : 0.01f * a2;
    a3 = a3 > 0.f ? a3 : 0.01f * a3;
    a4 = a4 > 0.f ? a4 : 0.01f * a4;
    a5 = a5 > 0.f ? a5 : 0.01f * a5;
    a6 = a6 > 0.f ? a6 : 0.01f * a6;
    a7 = a7 > 0.f ? a7 : 0.01f * a7;

    if (LAST) {
        float* orow = xout + (size_t)n * HIDDEN + l16 * 8;
        *(float4*)(orow + 0) = float4{a0, a1, a2, a3};
        *(float4*)(orow + 4) = float4{a4, a5, a6, a7};
    } else {
        uint4 packed;
        packed.x = (uint)f2bf(a0) | ((uint)f2bf(a1) << 16);
        packed.y = (uint)f2bf(a2) | ((uint)f2bf(a3) << 16);
        packed.z = (uint)f2bf(a4) | ((uint)f2bf(a5) << 16);
        packed.w = (uint)f2bf(a6) | ((uint)f2bf(a7) << 16);
        ((uint4*)(xb + (size_t)n * 64))[l16] = packed;
    }

    // energy tap: dot over this lane's 8 elems, reduce across the 16-lane group
    const float* wer = We_l + l16 * 8;
    float4 we0 = *(const float4*)(wer + 0);
    float4 we1 = *(const float4*)(wer + 4);
    float dot = a0 * we0.x + a1 * we0.y + a2 * we0.z + a3 * we0.w
              + a4 * we1.x + a5 * we1.y + a6 * we1.z + a7 * we1.w;
    #pragma unroll
    for (int off = 8; off > 0; off >>= 1) dot += __shfl_xor(dot, off);
    if (l16 == 0) energy[n] += (dot + be_l[0]) * temp_l[0];
}

extern "C" void kernel_launch(void* const* d_in, const int* in_sizes, int n_in,
                              void* d_out, int out_size, void* d_ws, size_t ws_size,
                              hipStream_t stream) {
    const float* x    = (const float*)d_in[0];
    const int*   src  = (const int*)d_in[1];
    const int*   dst  = (const int*)d_in[2];
    const float* w    = (const float*)d_in[3];
    const float* Ws   = (const float*)d_in[4];
    const float* bs   = (const float*)d_in[5];
    const float* We   = (const float*)d_in[6];
    const float* be   = (const float*)d_in[7];
    const float* temp = (const float*)d_in[8];

    float* energy = (float*)d_out;            // [N]
    float* xout   = (float*)d_out + N_NODES;  // [N,128] f32 final x
    uint* xb = (uint*)xout;                   // bf16 x scratch aliases xout

    // workspace (epack 16B-aligned after h; cnt/fillc adjacent for one memset)
    ushort* h      = (ushort*)d_ws;                       // MPAD*128 bf16 (25.6MB)
    int2*   epack  = (int2*)(h + (size_t)MPAD * HIDDEN);  // E (8B each)
    int*    cnt    = (int*)(epack + N_EDGES);
    int*    fillc  = cnt + N_NODES;
    int*    excl   = fillc + N_NODES;
    int*    bsums  = excl + N_NODES;                      // 128
    int*    rowptr = bsums + 128;                         // N+1
    ushort* whi    = (ushort*)(rowptr + N_NODES + 4);     // 4*128*128
    ushort* wlo    = whi + N_LAYERS * HIDDEN * HIDDEN;

    // ---- zero cnt+fillc in one shot ----
    hipMemsetAsync(cnt, 0, 2 * N_NODES * sizeof(int), stream);

    // ---- fused prologue: tap0+cast | count_dst | prep_w ----
    prologue<<<TAP0_BLOCKS + CNT_BLOCKS + PREPW_BLOCKS, 256, 0, stream>>>(
        x, We, be, temp, energy, xb, dst, cnt, Ws, whi, wlo);

    // ---- scan -> rowptr, then CSR fill ----
    int nblk = (N_NODES + 1023) / 1024;
    scan1<<<nblk, 256, 0, stream>>>(cnt, excl, bsums, N_NODES);
    scan2<<<1, 256, 0, stream>>>(bsums, nblk);
    scan3<<<(N_NODES + 1 + 255) / 256, 256, 0, stream>>>(excl, bsums, rowptr, N_NODES);
    fill_csr<<<(N_EDGES + 255) / 256, 256, 0, stream>>>(src, dst, w, rowptr, fillc, epack);

    // ---- layers ----
    int agg_blocks = (N_NODES * 16 + 255) / 256;   // 16 lanes per node
    for (int i = 0; i < N_LAYERS; ++i) {
        gemm_lds<<<(MPAD / 64), 256, 0, stream>>>(
            xb, whi + (size_t)i * HIDDEN * HIDDEN,
            wlo + (size_t)i * HIDDEN * HIDDEN, bs + (size_t)i * HIDDEN, h);
        if (i < N_LAYERS - 1) {
            agg_relu_tap<0><<<agg_blocks, 256, 0, stream>>>(
                h, rowptr, epack, We + (size_t)(i + 1) * HIDDEN, be + (i + 1),
                temp + (i + 1), xb, xout, energy);
        } else {
            agg_relu_tap<1><<<agg_blocks, 256, 0, stream>>>(
                h, rowptr, epack, We + (size_t)(i + 1) * HIDDEN, be + (i + 1),
                temp + (i + 1), xb, xout, energy);
        }
    }
}

// Round 10
// 298.096 us; speedup vs baseline: 1.0423x; 1.0423x over previous
//
#include <hip/hip_runtime.h>
#include <hip/hip_bf16.h>

#define N_NODES 100000
#define N_EDGES 600000
#define HIDDEN 128
#define N_LAYERS 4
#define MPAD 100096   // N_NODES rounded up to 128 (and to 64)

#define TAP0_BLOCKS ((N_NODES * 16) / 256)                       // 6250
#define CNT_BLOCKS ((N_EDGES + 255) / 256)                       // 2344
#define PREPW_BLOCKS ((N_LAYERS * HIDDEN * HIDDEN + 255) / 256)  // 256

typedef short bf16x8 __attribute__((ext_vector_type(8)));
typedef float f32x4 __attribute__((ext_vector_type(4)));
typedef float f32x8 __attribute__((ext_vector_type(8)));

__device__ inline ushort f2bf(float f) {
    __hip_bfloat16 h = __float2bfloat16(f);
    return *reinterpret_cast<ushort*>(&h);
}

__device__ inline float bfhi(uint u) { return __uint_as_float(u << 16); }
__device__ inline float bflo(uint u) { return __uint_as_float(u & 0xffff0000u); }

// ===========================================================================
// Prologue (fused independent prep): tap0+cast x0 | count_dst | prep_w
// tap0: 16 lanes per node, f32x8 per lane, 4-step shfl reduce (round-8 fix).
// ===========================================================================
__global__ void prologue(const float* __restrict__ x, const float* __restrict__ We,
                         const float* __restrict__ be, const float* __restrict__ temp,
                         float* __restrict__ energy, uint* __restrict__ xb,
                         const int* __restrict__ dst, int* __restrict__ cnt,
                         const float* __restrict__ Ws, ushort* __restrict__ whi,
                         ushort* __restrict__ wlo) {
    int b = blockIdx.x;
    if (b < TAP0_BLOCKS) {
        int gtid = b * 256 + threadIdx.x;
        int n = gtid >> 4, l16 = gtid & 15;
        f32x8 v = *(const f32x8*)(x + (size_t)n * HIDDEN + l16 * 8);
        uint4 packed;
        packed.x = (uint)f2bf(v[0]) | ((uint)f2bf(v[1]) << 16);
        packed.y = (uint)f2bf(v[2]) | ((uint)f2bf(v[3]) << 16);
        packed.z = (uint)f2bf(v[4]) | ((uint)f2bf(v[5]) << 16);
        packed.w = (uint)f2bf(v[6]) | ((uint)f2bf(v[7]) << 16);
        ((uint4*)(xb + (size_t)n * 64))[l16] = packed;
        f32x8 we = *(const f32x8*)(We + l16 * 8);
        float dot = v[0] * we[0] + v[1] * we[1] + v[2] * we[2] + v[3] * we[3]
                  + v[4] * we[4] + v[5] * we[5] + v[6] * we[6] + v[7] * we[7];
        #pragma unroll
        for (int off = 8; off > 0; off >>= 1) dot += __shfl_xor(dot, off);
        if (l16 == 0) energy[n] = (dot + be[0]) * temp[0];
    } else if (b < TAP0_BLOCKS + CNT_BLOCKS) {
        int e = (b - TAP0_BLOCKS) * 256 + threadIdx.x;
        if (e < N_EDGES) atomicAdd(&cnt[dst[e]], 1);
    } else {
        int idx = (b - TAP0_BLOCKS - CNT_BLOCKS) * 256 + threadIdx.x;
        if (idx < N_LAYERS * HIDDEN * HIDDEN) {
            int l = idx >> 14;
            int r = idx & 16383;
            int c = r >> 7, k = r & 127;
            float v = Ws[(l << 14) + k * HIDDEN + c];
            ushort hi = f2bf(v);
            float hif = __uint_as_float(((uint)hi) << 16);
            whi[idx] = hi;
            wlo[idx] = f2bf(v - hif);
        }
    }
}

// ===========================================================================
// Exclusive scan over cnt -> rowptr (scan1 + merged scan23)
// ===========================================================================
__global__ void scan1(const int* __restrict__ cnt, int* __restrict__ excl,
                      int* __restrict__ bsums, int n) {
    __shared__ int lds[8];
    int t = threadIdx.x;
    int base = blockIdx.x * 1024 + t * 4;
    int v0 = (base + 0 < n) ? cnt[base + 0] : 0;
    int v1 = (base + 1 < n) ? cnt[base + 1] : 0;
    int v2 = (base + 2 < n) ? cnt[base + 2] : 0;
    int v3 = (base + 3 < n) ? cnt[base + 3] : 0;
    int tsum = v0 + v1 + v2 + v3;
    int lane = t & 63, wv = t >> 6;
    int s = tsum;
    #pragma unroll
    for (int off = 1; off < 64; off <<= 1) {
        int u = __shfl_up(s, off);
        if (lane >= off) s += u;
    }
    if (lane == 63) lds[wv] = s;
    __syncthreads();
    if (t == 0) {
        int a = 0;
        #pragma unroll
        for (int i = 0; i < 4; ++i) { int bb = lds[i]; lds[i] = a; a += bb; }
        lds[4] = a;
    }
    __syncthreads();
    int excl_t = (s - tsum) + lds[wv];
    if (base + 0 < n) excl[base + 0] = excl_t;
    if (base + 1 < n) excl[base + 1] = excl_t + v0;
    if (base + 2 < n) excl[base + 2] = excl_t + v0 + v1;
    if (base + 3 < n) excl[base + 3] = excl_t + v0 + v1 + v2;
    if (t == 0) bsums[blockIdx.x] = lds[4];
}

// Merged scan2+scan3: each block redundantly exclusive-scans the <=128 block
// sums in LDS (98 ints -- trivial), then emits its 256 rowptr entries.
__global__ void scan23(const int* __restrict__ excl, const int* __restrict__ bsums,
                       int* __restrict__ rowptr, int n, int nb) {
    __shared__ int bp[128];
    int t = threadIdx.x;
    if (t < nb) bp[t] = bsums[t];
    __syncthreads();
    if (t == 0) {
        int a = 0;
        for (int i = 0; i < nb; ++i) { int v = bp[i]; bp[i] = a; a += v; }
    }
    __syncthreads();
    int i = blockIdx.x * blockDim.x + t;
    if (i < n) rowptr[i] = excl[i] + bp[i >> 10];
    else if (i == n) rowptr[n] = N_EDGES;
}

__global__ void fill_csr(const int* __restrict__ src, const int* __restrict__ dst,
                         const float* __restrict__ w, const int* __restrict__ rowptr,
                         int* __restrict__ fillc, int2* __restrict__ epack) {
    int e = blockIdx.x * blockDim.x + threadIdx.x;
    if (e >= N_EDGES) return;
    int d = dst[e];
    int pos = atomicAdd(&fillc[d], 1);
    int slot = rowptr[d] + pos;
    epack[slot] = make_int2(src[e], __float_as_int(w[e]));
}

// ===========================================================================
// LDS-staged MFMA GEMM: x plain bf16, W split (2 products Whi*x + Wlo*x).
// Block: 256 thr / 4 waves; tile = 64 nodes x 128 cols; LDS 16 KB,
// XOR-swizzled (col16B ^= (row&7)) -> conflict-free ds_read_b128.
// ===========================================================================
__global__ __launch_bounds__(256) void gemm_lds(
    const uint* __restrict__ xb,
    const ushort* __restrict__ whi, const ushort* __restrict__ wlo,
    const float* __restrict__ b, ushort* __restrict__ h) {
    __shared__ uint4 sx4[1024];          // 16 KB
    char* sxb = (char*)sx4;
    int t = threadIdx.x;
    int lane = t & 63, wv = t >> 6;
    int l15 = lane & 15, l4 = lane >> 4;
    int row0 = blockIdx.x * 64;
    int c0 = wv * 32;

    bf16x8 Ah[2][4], Al[2][4];
    #pragma unroll
    for (int m = 0; m < 2; ++m) {
        int c = c0 + m * 16 + l15;
        #pragma unroll
        for (int s = 0; s < 4; ++s) {
            int off = c * HIDDEN + s * 32 + l4 * 8;
            Ah[m][s] = *(const bf16x8*)(whi + off);
            Al[m][s] = *(const bf16x8*)(wlo + off);
        }
    }

    #pragma unroll
    for (int j = 0; j < 4; ++j) {
        int c = j * 256 + t;
        int row = c >> 4;
        int colb = (c & 15) * 16;
        int grow = row0 + row;
        if (grow >= N_NODES) grow = N_NODES - 1;
        uint4 v = *(const uint4*)((const char*)xb + (size_t)grow * 256 + colb);
        *(uint4*)(sxb + row * 256 + (colb ^ ((row & 7) << 4))) = v;
    }
    __syncthreads();

    f32x4 acc[2][4];
    #pragma unroll
    for (int m = 0; m < 2; ++m)
        #pragma unroll
        for (int n = 0; n < 4; ++n)
            acc[m][n] = f32x4{0.f, 0.f, 0.f, 0.f};

    #pragma unroll
    for (int n = 0; n < 4; ++n) {
        int row = n * 16 + l15;
        int rsw = (row & 7) << 4;
        #pragma unroll
        for (int s = 0; s < 4; ++s) {
            bf16x8 bh = *(const bf16x8*)(sxb + row * 256 + ((s * 64 + l4 * 16) ^ rsw));
            #pragma unroll
            for (int m = 0; m < 2; ++m) {
                acc[m][n] = __builtin_amdgcn_mfma_f32_16x16x32_bf16(Ah[m][s], bh, acc[m][n], 0, 0, 0);
                acc[m][n] = __builtin_amdgcn_mfma_f32_16x16x32_bf16(Al[m][s], bh, acc[m][n], 0, 0, 0);
            }
        }
    }

    #pragma unroll
    for (int m = 0; m < 2; ++m) {
        f32x4 bias = *(const f32x4*)(b + c0 + m * 16 + l4 * 4);
        #pragma unroll
        for (int n = 0; n < 4; ++n) {
            int node = row0 + n * 16 + l15;
            f32x4 r = acc[m][n] + bias;
            uint2 packed;
            packed.x = (uint)f2bf(r[0]) | ((uint)f2bf(r[1]) << 16);
            packed.y = (uint)f2bf(r[2]) | ((uint)f2bf(r[3]) << 16);
            *(uint2*)(h + (size_t)node * HIDDEN + c0 + m * 16 + l4 * 4) = packed;
        }
    }
}

// ===========================================================================
// Fused CSR aggregation + leaky-relu + energy tap (round-8 proven form).
// 16 lanes per node, uint4 per lane; ONE shared 4-wide loop body (round-9
// lesson: static degree tiers diverge the 4 groups within a wave -> slower).
// LAST=0: write bf16 x (uint4, coalesced). LAST=1: write f32 x to d_out.
// ===========================================================================
template <int LAST>
__global__ void agg_relu_tap(const ushort* __restrict__ h, const int* __restrict__ rowptr,
                             const int2* __restrict__ epack,
                             const float* __restrict__ We_l, const float* __restrict__ be_l,
                             const float* __restrict__ temp_l,
                             uint* __restrict__ xb, float* __restrict__ xout,
                             float* __restrict__ energy) {
    int gtid = blockIdx.x * blockDim.x + threadIdx.x;
    int n = gtid >> 4;          // one 16-lane group per node
    int l16 = gtid & 15;
    if (n >= N_NODES) return;
    int j0 = rowptr[n], j1 = rowptr[n + 1];

    float a0 = 0.f, a1 = 0.f, a2 = 0.f, a3 = 0.f;
    float a4 = 0.f, a5 = 0.f, a6 = 0.f, a7 = 0.f;
    const char* hrow = (const char*)h;
    int cb = l16 * 16;          // byte offset of this lane's 16B chunk

    int j = j0;
    for (; j + 4 <= j1; j += 4) {
        int2 p0 = epack[j], p1 = epack[j + 1], p2 = epack[j + 2], p3 = epack[j + 3];
        uint4 u0 = *(const uint4*)(hrow + (size_t)p0.x * 256 + cb);
        uint4 u1 = *(const uint4*)(hrow + (size_t)p1.x * 256 + cb);
        uint4 u2 = *(const uint4*)(hrow + (size_t)p2.x * 256 + cb);
        uint4 u3 = *(const uint4*)(hrow + (size_t)p3.x * 256 + cb);
        float w0 = __int_as_float(p0.y), w1 = __int_as_float(p1.y);
        float w2 = __int_as_float(p2.y), w3 = __int_as_float(p3.y);
        a0 += bfhi(u0.x) * w0 + bfhi(u1.x) * w1 + bfhi(u2.x) * w2 + bfhi(u3.x) * w3;
        a1 += bflo(u0.x) * w0 + bflo(u1.x) * w1 + bflo(u2.x) * w2 + bflo(u3.x) * w3;
        a2 += bfhi(u0.y) * w0 + bfhi(u1.y) * w1 + bfhi(u2.y) * w2 + bfhi(u3.y) * w3;
        a3 += bflo(u0.y) * w0 + bflo(u1.y) * w1 + bflo(u2.y) * w2 + bflo(u3.y) * w3;
        a4 += bfhi(u0.z) * w0 + bfhi(u1.z) * w1 + bfhi(u2.z) * w2 + bfhi(u3.z) * w3;
        a5 += bflo(u0.z) * w0 + bflo(u1.z) * w1 + bflo(u2.z) * w2 + bflo(u3.z) * w3;
        a6 += bfhi(u0.w) * w0 + bfhi(u1.w) * w1 + bfhi(u2.w) * w2 + bfhi(u3.w) * w3;
        a7 += bflo(u0.w) * w0 + bflo(u1.w) * w1 + bflo(u2.w) * w2 + bflo(u3.w) * w3;
    }
    if (j + 2 <= j1) {
        int2 p0 = epack[j], p1 = epack[j + 1];
        uint4 u0 = *(const uint4*)(hrow + (size_t)p0.x * 256 + cb);
        uint4 u1 = *(const uint4*)(hrow + (size_t)p1.x * 256 + cb);
        float w0 = __int_as_float(p0.y), w1 = __int_as_float(p1.y);
        a0 += bfhi(u0.x) * w0 + bfhi(u1.x) * w1;
        a1 += bflo(u0.x) * w0 + bflo(u1.x) * w1;
        a2 += bfhi(u0.y) * w0 + bfhi(u1.y) * w1;
        a3 += bflo(u0.y) * w0 + bflo(u1.y) * w1;
        a4 += bfhi(u0.z) * w0 + bfhi(u1.z) * w1;
        a5 += bflo(u0.z) * w0 + bflo(u1.z) * w1;
        a6 += bfhi(u0.w) * w0 + bfhi(u1.w) * w1;
        a7 += bflo(u0.w) * w0 + bflo(u1.w) * w1;
        j += 2;
    }
    if (j < j1) {
        int2 p0 = epack[j];
        uint4 u0 = *(const uint4*)(hrow + (size_t)p0.x * 256 + cb);
        float w0 = __int_as_float(p0.y);
        a0 += bfhi(u0.x) * w0;
        a1 += bflo(u0.x) * w0;
        a2 += bfhi(u0.y) * w0;
        a3 += bflo(u0.y) * w0;
        a4 += bfhi(u0.z) * w0;
        a5 += bflo(u0.z) * w0;
        a6 += bfhi(u0.w) * w0;
        a7 += bflo(u0.w) * w0;
    }

    a0 = a0 > 0.f ? a0 : 0.01f * a0;
    a1 = a1 > 0.f ? a1 : 0.01f * a1;
    a2 = a2 > 0.f ? a2 : 0.01f * a2;
    a3 = a3 > 0.f ? a3 : 0.01f * a3;
    a4 = a4 > 0.f ? a4 : 0.01f * a4;
    a5 = a5 > 0.f ? a5 : 0.01f * a5;
    a6 = a6 > 0.f ? a6 : 0.01f * a6;
    a7 = a7 > 0.f ? a7 : 0.01f * a7;

    if (LAST) {
        float* orow = xout + (size_t)n * HIDDEN + l16 * 8;
        *(float4*)(orow + 0) = float4{a0, a1, a2, a3};
        *(float4*)(orow + 4) = float4{a4, a5, a6, a7};
    } else {
        uint4 packed;
        packed.x = (uint)f2bf(a0) | ((uint)f2bf(a1) << 16);
        packed.y = (uint)f2bf(a2) | ((uint)f2bf(a3) << 16);
        packed.z = (uint)f2bf(a4) | ((uint)f2bf(a5) << 16);
        packed.w = (uint)f2bf(a6) | ((uint)f2bf(a7) << 16);
        ((uint4*)(xb + (size_t)n * 64))[l16] = packed;
    }

    const float* wer = We_l + l16 * 8;
    float4 we0 = *(const float4*)(wer + 0);
    float4 we1 = *(const float4*)(wer + 4);
    float dot = a0 * we0.x + a1 * we0.y + a2 * we0.z + a3 * we0.w
              + a4 * we1.x + a5 * we1.y + a6 * we1.z + a7 * we1.w;
    #pragma unroll
    for (int off = 8; off > 0; off >>= 1) dot += __shfl_xor(dot, off);
    if (l16 == 0) energy[n] += (dot + be_l[0]) * temp_l[0];
}

extern "C" void kernel_launch(void* const* d_in, const int* in_sizes, int n_in,
                              void* d_out, int out_size, void* d_ws, size_t ws_size,
                              hipStream_t stream) {
    const float* x    = (const float*)d_in[0];
    const int*   src  = (const int*)d_in[1];
    const int*   dst  = (const int*)d_in[2];
    const float* w    = (const float*)d_in[3];
    const float* Ws   = (const float*)d_in[4];
    const float* bs   = (const float*)d_in[5];
    const float* We   = (const float*)d_in[6];
    const float* be   = (const float*)d_in[7];
    const float* temp = (const float*)d_in[8];

    float* energy = (float*)d_out;            // [N]
    float* xout   = (float*)d_out + N_NODES;  // [N,128] f32 final x
    uint* xb = (uint*)xout;                   // bf16 x scratch aliases xout

    // workspace (epack 16B-aligned after h; cnt/fillc adjacent for one memset)
    ushort* h      = (ushort*)d_ws;                       // MPAD*128 bf16 (25.6MB)
    int2*   epack  = (int2*)(h + (size_t)MPAD * HIDDEN);  // E (8B each)
    int*    cnt    = (int*)(epack + N_EDGES);
    int*    fillc  = cnt + N_NODES;
    int*    excl   = fillc + N_NODES;
    int*    bsums  = excl + N_NODES;                      // 128
    int*    rowptr = bsums + 128;                         // N+1
    ushort* whi    = (ushort*)(rowptr + N_NODES + 4);     // 4*128*128
    ushort* wlo    = whi + N_LAYERS * HIDDEN * HIDDEN;

    // ---- zero cnt+fillc in one shot ----
    hipMemsetAsync(cnt, 0, 2 * N_NODES * sizeof(int), stream);

    // ---- fused prologue: tap0+cast | count_dst | prep_w ----
    prologue<<<TAP0_BLOCKS + CNT_BLOCKS + PREPW_BLOCKS, 256, 0, stream>>>(
        x, We, be, temp, energy, xb, dst, cnt, Ws, whi, wlo);

    // ---- scan -> rowptr, then CSR fill ----
    int nblk = (N_NODES + 1023) / 1024;   // 98
    scan1<<<nblk, 256, 0, stream>>>(cnt, excl, bsums, N_NODES);
    scan23<<<(N_NODES + 1 + 255) / 256, 256, 0, stream>>>(excl, bsums, rowptr, N_NODES, nblk);
    fill_csr<<<(N_EDGES + 255) / 256, 256, 0, stream>>>(src, dst, w, rowptr, fillc, epack);

    // ---- layers ----
    int agg_blocks = (N_NODES * 16 + 255) / 256;   // 16 lanes per node
    for (int i = 0; i < N_LAYERS; ++i) {
        gemm_lds<<<(MPAD / 64), 256, 0, stream>>>(
            xb, whi + (size_t)i * HIDDEN * HIDDEN,
            wlo + (size_t)i * HIDDEN * HIDDEN, bs + (size_t)i * HIDDEN, h);
        if (i < N_LAYERS - 1) {
            agg_relu_tap<0><<<agg_blocks, 256, 0, stream>>>(
                h, rowptr, epack, We + (size_t)(i + 1) * HIDDEN, be + (i + 1),
                temp + (i + 1), xb, xout, energy);
        } else {
            agg_relu_tap<1><<<agg_blocks, 256, 0, stream>>>(
                h, rowptr, epack, We + (size_t)(i + 1) * HIDDEN, be + (i + 1),
                temp + (i + 1), xb, xout, energy);
        }
    }
}

// Round 11
// 289.792 us; speedup vs baseline: 1.0722x; 1.0287x over previous
//
#include <hip/hip_runtime.h>
#include <hip/hip_bf16.h>

#define N_NODES 100000
#define N_EDGES 600000
#define HIDDEN 128
#define N_LAYERS 4
#define MPAD 100096   // N_NODES rounded up to 128 (and to 64)

#define TAP0_BLOCKS ((N_NODES * 16) / 256)                       // 6250
#define CNT_BLOCKS ((N_EDGES + 255) / 256)                       // 2344
#define PREPW_BLOCKS ((N_LAYERS * HIDDEN * HIDDEN + 255) / 256)  // 256
#define GEMM_BLOCKS (MPAD / 64)                                  // 1564

typedef short bf16x8 __attribute__((ext_vector_type(8)));
typedef float f32x4 __attribute__((ext_vector_type(4)));
typedef float f32x8 __attribute__((ext_vector_type(8)));

__device__ inline ushort f2bf(float f) {
    __hip_bfloat16 h = __float2bfloat16(f);
    return *reinterpret_cast<ushort*>(&h);
}

__device__ inline float bfhi(uint u) { return __uint_as_float(u << 16); }
__device__ inline float bflo(uint u) { return __uint_as_float(u & 0xffff0000u); }

// Shared gather body (round-8 proven): 16 lanes/node, uint4/lane, exact-width
// 4/2/1 rounds, ONE shared loop body (no degree tiers - round-9 lesson).
#define FMA8(U, P) { float wk = __int_as_float(P.y); \
    a[0] += bfhi(U.x) * wk; a[1] += bflo(U.x) * wk; \
    a[2] += bfhi(U.y) * wk; a[3] += bflo(U.y) * wk; \
    a[4] += bfhi(U.z) * wk; a[5] += bflo(U.z) * wk; \
    a[6] += bfhi(U.w) * wk; a[7] += bflo(U.w) * wk; }

__device__ __forceinline__ void gather_agg(const char* __restrict__ hrow,
                                           const int2* __restrict__ epack,
                                           int j0, int j1, int cb, float* a) {
    int j = j0;
    for (; j + 4 <= j1; j += 4) {
        int2 p0 = epack[j], p1 = epack[j + 1], p2 = epack[j + 2], p3 = epack[j + 3];
        uint4 u0 = *(const uint4*)(hrow + (size_t)p0.x * 256 + cb);
        uint4 u1 = *(const uint4*)(hrow + (size_t)p1.x * 256 + cb);
        uint4 u2 = *(const uint4*)(hrow + (size_t)p2.x * 256 + cb);
        uint4 u3 = *(const uint4*)(hrow + (size_t)p3.x * 256 + cb);
        FMA8(u0, p0); FMA8(u1, p1); FMA8(u2, p2); FMA8(u3, p3);
    }
    if (j + 2 <= j1) {
        int2 p0 = epack[j], p1 = epack[j + 1];
        uint4 u0 = *(const uint4*)(hrow + (size_t)p0.x * 256 + cb);
        uint4 u1 = *(const uint4*)(hrow + (size_t)p1.x * 256 + cb);
        FMA8(u0, p0); FMA8(u1, p1);
        j += 2;
    }
    if (j < j1) {
        int2 p0 = epack[j];
        uint4 u0 = *(const uint4*)(hrow + (size_t)p0.x * 256 + cb);
        FMA8(u0, p0);
    }
}

// ===========================================================================
// Prologue (fused independent prep): tap0+cast x0 | count_dst | prep_w
// ===========================================================================
__global__ void prologue(const float* __restrict__ x, const float* __restrict__ We,
                         const float* __restrict__ be, const float* __restrict__ temp,
                         float* __restrict__ energy, uint* __restrict__ xb,
                         const int* __restrict__ dst, int* __restrict__ cnt,
                         const float* __restrict__ Ws, ushort* __restrict__ whi,
                         ushort* __restrict__ wlo) {
    int b = blockIdx.x;
    if (b < TAP0_BLOCKS) {
        int gtid = b * 256 + threadIdx.x;
        int n = gtid >> 4, l16 = gtid & 15;
        f32x8 v = *(const f32x8*)(x + (size_t)n * HIDDEN + l16 * 8);
        uint4 packed;
        packed.x = (uint)f2bf(v[0]) | ((uint)f2bf(v[1]) << 16);
        packed.y = (uint)f2bf(v[2]) | ((uint)f2bf(v[3]) << 16);
        packed.z = (uint)f2bf(v[4]) | ((uint)f2bf(v[5]) << 16);
        packed.w = (uint)f2bf(v[6]) | ((uint)f2bf(v[7]) << 16);
        ((uint4*)(xb + (size_t)n * 64))[l16] = packed;
        f32x8 we = *(const f32x8*)(We + l16 * 8);
        float dot = v[0] * we[0] + v[1] * we[1] + v[2] * we[2] + v[3] * we[3]
                  + v[4] * we[4] + v[5] * we[5] + v[6] * we[6] + v[7] * we[7];
        #pragma unroll
        for (int off = 8; off > 0; off >>= 1) dot += __shfl_xor(dot, off);
        if (l16 == 0) energy[n] = (dot + be[0]) * temp[0];
    } else if (b < TAP0_BLOCKS + CNT_BLOCKS) {
        int e = (b - TAP0_BLOCKS) * 256 + threadIdx.x;
        if (e < N_EDGES) atomicAdd(&cnt[dst[e]], 1);
    } else {
        int idx = (b - TAP0_BLOCKS - CNT_BLOCKS) * 256 + threadIdx.x;
        if (idx < N_LAYERS * HIDDEN * HIDDEN) {
            int l = idx >> 14;
            int r = idx & 16383;
            int c = r >> 7, k = r & 127;
            float v = Ws[(l << 14) + k * HIDDEN + c];
            ushort hi = f2bf(v);
            float hif = __uint_as_float(((uint)hi) << 16);
            whi[idx] = hi;
            wlo[idx] = f2bf(v - hif);
        }
    }
}

// ===========================================================================
// Exclusive scan over cnt -> rowptr (scan1 + merged scan23)
// ===========================================================================
__global__ void scan1(const int* __restrict__ cnt, int* __restrict__ excl,
                      int* __restrict__ bsums, int n) {
    __shared__ int lds[8];
    int t = threadIdx.x;
    int base = blockIdx.x * 1024 + t * 4;
    int v0 = (base + 0 < n) ? cnt[base + 0] : 0;
    int v1 = (base + 1 < n) ? cnt[base + 1] : 0;
    int v2 = (base + 2 < n) ? cnt[base + 2] : 0;
    int v3 = (base + 3 < n) ? cnt[base + 3] : 0;
    int tsum = v0 + v1 + v2 + v3;
    int lane = t & 63, wv = t >> 6;
    int s = tsum;
    #pragma unroll
    for (int off = 1; off < 64; off <<= 1) {
        int u = __shfl_up(s, off);
        if (lane >= off) s += u;
    }
    if (lane == 63) lds[wv] = s;
    __syncthreads();
    if (t == 0) {
        int a = 0;
        #pragma unroll
        for (int i = 0; i < 4; ++i) { int bb = lds[i]; lds[i] = a; a += bb; }
        lds[4] = a;
    }
    __syncthreads();
    int excl_t = (s - tsum) + lds[wv];
    if (base + 0 < n) excl[base + 0] = excl_t;
    if (base + 1 < n) excl[base + 1] = excl_t + v0;
    if (base + 2 < n) excl[base + 2] = excl_t + v0 + v1;
    if (base + 3 < n) excl[base + 3] = excl_t + v0 + v1 + v2;
    if (t == 0) bsums[blockIdx.x] = lds[4];
}

__global__ void scan23(const int* __restrict__ excl, const int* __restrict__ bsums,
                       int* __restrict__ rowptr, int n, int nb) {
    __shared__ int bp[128];
    int t = threadIdx.x;
    if (t < nb) bp[t] = bsums[t];
    __syncthreads();
    if (t == 0) {
        int a = 0;
        for (int i = 0; i < nb; ++i) { int v = bp[i]; bp[i] = a; a += v; }
    }
    __syncthreads();
    int i = blockIdx.x * blockDim.x + t;
    if (i < n) rowptr[i] = excl[i] + bp[i >> 10];
    else if (i == n) rowptr[n] = N_EDGES;
}

// ===========================================================================
// Fused fill_csr + layer-0 GEMM (disjoint deps -> co-scheduled block ranges;
// scatter-latency fill waves hide under gemm compute).
// Blocks [0, GEMM_BLOCKS): gemm0 (xb -> h0). Rest: CSR fill.
// ===========================================================================
__global__ __launch_bounds__(256) void fill_gemm0(
    const int* __restrict__ src, const int* __restrict__ dst,
    const float* __restrict__ w, const int* __restrict__ rowptr,
    int* __restrict__ fillc, int2* __restrict__ epack,
    const uint* __restrict__ xb,
    const ushort* __restrict__ whi, const ushort* __restrict__ wlo,
    const float* __restrict__ b, ushort* __restrict__ h) {
    int t = threadIdx.x;
    if (blockIdx.x >= GEMM_BLOCKS) {
        int e = (blockIdx.x - GEMM_BLOCKS) * 256 + t;
        if (e < N_EDGES) {
            int d = dst[e];
            int pos = atomicAdd(&fillc[d], 1);
            epack[rowptr[d] + pos] = make_int2(src[e], __float_as_int(w[e]));
        }
        return;
    }
    __shared__ uint4 sx4[1024];          // 16 KB
    char* sxb = (char*)sx4;
    int lane = t & 63, wv = t >> 6;
    int l15 = lane & 15, l4 = lane >> 4;
    int row0 = blockIdx.x * 64;
    int c0 = wv * 32;

    bf16x8 Ah[2][4], Al[2][4];
    #pragma unroll
    for (int m = 0; m < 2; ++m) {
        int c = c0 + m * 16 + l15;
        #pragma unroll
        for (int s = 0; s < 4; ++s) {
            int off = c * HIDDEN + s * 32 + l4 * 8;
            Ah[m][s] = *(const bf16x8*)(whi + off);
            Al[m][s] = *(const bf16x8*)(wlo + off);
        }
    }

    #pragma unroll
    for (int j = 0; j < 4; ++j) {
        int c = j * 256 + t;
        int row = c >> 4;
        int colb = (c & 15) * 16;
        int grow = row0 + row;
        if (grow >= N_NODES) grow = N_NODES - 1;
        uint4 v = *(const uint4*)((const char*)xb + (size_t)grow * 256 + colb);
        *(uint4*)(sxb + row * 256 + (colb ^ ((row & 7) << 4))) = v;
    }
    __syncthreads();

    f32x4 acc[2][4];
    #pragma unroll
    for (int m = 0; m < 2; ++m)
        #pragma unroll
        for (int n = 0; n < 4; ++n)
            acc[m][n] = f32x4{0.f, 0.f, 0.f, 0.f};

    #pragma unroll
    for (int n = 0; n < 4; ++n) {
        int row = n * 16 + l15;
        int rsw = (row & 7) << 4;
        #pragma unroll
        for (int s = 0; s < 4; ++s) {
            bf16x8 bh = *(const bf16x8*)(sxb + row * 256 + ((s * 64 + l4 * 16) ^ rsw));
            #pragma unroll
            for (int m = 0; m < 2; ++m) {
                acc[m][n] = __builtin_amdgcn_mfma_f32_16x16x32_bf16(Ah[m][s], bh, acc[m][n], 0, 0, 0);
                acc[m][n] = __builtin_amdgcn_mfma_f32_16x16x32_bf16(Al[m][s], bh, acc[m][n], 0, 0, 0);
            }
        }
    }

    #pragma unroll
    for (int m = 0; m < 2; ++m) {
        f32x4 bias = *(const f32x4*)(b + c0 + m * 16 + l4 * 4);
        #pragma unroll
        for (int n = 0; n < 4; ++n) {
            int node = row0 + n * 16 + l15;
            f32x4 r = acc[m][n] + bias;
            uint2 packed;
            packed.x = (uint)f2bf(r[0]) | ((uint)f2bf(r[1]) << 16);
            packed.y = (uint)f2bf(r[2]) | ((uint)f2bf(r[3]) << 16);
            *(uint2*)(h + (size_t)node * HIDDEN + c0 + m * 16 + l4 * 4) = packed;
        }
    }
}

// ===========================================================================
// Fused agg_i + gemm_{i+1}: block owns 64 nodes; phase A aggregates them
// (relu + tap) straight into the swizzled LDS tile (xb round-trip deleted),
// phase B runs the MFMA gemm from LDS into h_next. h ping-pongs across
// layers (agg reads h_prev while gemm writes h_next).
// ===========================================================================
__global__ __launch_bounds__(256) void agg_gemm(
    const ushort* __restrict__ hprev, const int* __restrict__ rowptr,
    const int2* __restrict__ epack,
    const float* __restrict__ We_l, const float* __restrict__ be_l,
    const float* __restrict__ temp_l, float* __restrict__ energy,
    const ushort* __restrict__ whi, const ushort* __restrict__ wlo,
    const float* __restrict__ b, ushort* __restrict__ hnext) {
    __shared__ uint4 sx4[1024];          // 16 KB
    char* sxb = (char*)sx4;
    int t = threadIdx.x;
    int row0 = blockIdx.x * 64;
    int g = t >> 4, l16 = t & 15;
    int cb = l16 * 16;
    const char* hrow = (const char*)hprev;

    // ---- phase A: aggregate 64 nodes (16 groups x 4 passes) ----
    #pragma unroll 1
    for (int p = 0; p < 4; ++p) {
        int n = row0 + p * 16 + g;
        float a[8] = {0.f, 0.f, 0.f, 0.f, 0.f, 0.f, 0.f, 0.f};
        if (n < N_NODES) {
            int j0 = rowptr[n], j1 = rowptr[n + 1];
            gather_agg(hrow, epack, j0, j1, cb, a);
            #pragma unroll
            for (int q = 0; q < 8; ++q) a[q] = a[q] > 0.f ? a[q] : 0.01f * a[q];
            const float* wer = We_l + l16 * 8;
            float4 we0 = *(const float4*)(wer + 0);
            float4 we1 = *(const float4*)(wer + 4);
            float dot = a[0] * we0.x + a[1] * we0.y + a[2] * we0.z + a[3] * we0.w
                      + a[4] * we1.x + a[5] * we1.y + a[6] * we1.z + a[7] * we1.w;
            #pragma unroll
            for (int off = 8; off > 0; off >>= 1) dot += __shfl_xor(dot, off);
            if (l16 == 0) energy[n] += (dot + be_l[0]) * temp_l[0];
        }
        uint4 packed;
        packed.x = (uint)f2bf(a[0]) | ((uint)f2bf(a[1]) << 16);
        packed.y = (uint)f2bf(a[2]) | ((uint)f2bf(a[3]) << 16);
        packed.z = (uint)f2bf(a[4]) | ((uint)f2bf(a[5]) << 16);
        packed.w = (uint)f2bf(a[6]) | ((uint)f2bf(a[7]) << 16);
        int r = p * 16 + g;
        *(uint4*)(sxb + r * 256 + (cb ^ ((r & 7) << 4))) = packed;
    }

    // ---- phase B: gemm from LDS (W frags loaded after phase A: short live range) ----
    int lane = t & 63, wv = t >> 6;
    int l15 = lane & 15, l4 = lane >> 4;
    int c0 = wv * 32;
    bf16x8 Ah[2][4], Al[2][4];
    #pragma unroll
    for (int m = 0; m < 2; ++m) {
        int c = c0 + m * 16 + l15;
        #pragma unroll
        for (int s = 0; s < 4; ++s) {
            int off = c * HIDDEN + s * 32 + l4 * 8;
            Ah[m][s] = *(const bf16x8*)(whi + off);
            Al[m][s] = *(const bf16x8*)(wlo + off);
        }
    }
    __syncthreads();

    f32x4 acc[2][4];
    #pragma unroll
    for (int m = 0; m < 2; ++m)
        #pragma unroll
        for (int n = 0; n < 4; ++n)
            acc[m][n] = f32x4{0.f, 0.f, 0.f, 0.f};

    #pragma unroll
    for (int n = 0; n < 4; ++n) {
        int row = n * 16 + l15;
        int rsw = (row & 7) << 4;
        #pragma unroll
        for (int s = 0; s < 4; ++s) {
            bf16x8 bh = *(const bf16x8*)(sxb + row * 256 + ((s * 64 + l4 * 16) ^ rsw));
            #pragma unroll
            for (int m = 0; m < 2; ++m) {
                acc[m][n] = __builtin_amdgcn_mfma_f32_16x16x32_bf16(Ah[m][s], bh, acc[m][n], 0, 0, 0);
                acc[m][n] = __builtin_amdgcn_mfma_f32_16x16x32_bf16(Al[m][s], bh, acc[m][n], 0, 0, 0);
            }
        }
    }

    #pragma unroll
    for (int m = 0; m < 2; ++m) {
        f32x4 bias = *(const f32x4*)(b + c0 + m * 16 + l4 * 4);
        #pragma unroll
        for (int n = 0; n < 4; ++n) {
            int node = row0 + n * 16 + l15;
            f32x4 r = acc[m][n] + bias;
            uint2 packed;
            packed.x = (uint)f2bf(r[0]) | ((uint)f2bf(r[1]) << 16);
            packed.y = (uint)f2bf(r[2]) | ((uint)f2bf(r[3]) << 16);
            *(uint2*)(hnext + (size_t)node * HIDDEN + c0 + m * 16 + l4 * 4) = packed;
        }
    }
}

// ===========================================================================
// Final aggregation: relu + tap4 + f32 x out (round-8/10 proven form).
// ===========================================================================
__global__ void agg_final(const ushort* __restrict__ h, const int* __restrict__ rowptr,
                          const int2* __restrict__ epack,
                          const float* __restrict__ We_l, const float* __restrict__ be_l,
                          const float* __restrict__ temp_l,
                          float* __restrict__ xout, float* __restrict__ energy) {
    int gtid = blockIdx.x * blockDim.x + threadIdx.x;
    int n = gtid >> 4;
    int l16 = gtid & 15;
    if (n >= N_NODES) return;
    int j0 = rowptr[n], j1 = rowptr[n + 1];
    int cb = l16 * 16;
    float a[8] = {0.f, 0.f, 0.f, 0.f, 0.f, 0.f, 0.f, 0.f};
    gather_agg((const char*)h, epack, j0, j1, cb, a);
    #pragma unroll
    for (int q = 0; q < 8; ++q) a[q] = a[q] > 0.f ? a[q] : 0.01f * a[q];

    float* orow = xout + (size_t)n * HIDDEN + l16 * 8;
    *(float4*)(orow + 0) = float4{a[0], a[1], a[2], a[3]};
    *(float4*)(orow + 4) = float4{a[4], a[5], a[6], a[7]};

    const float* wer = We_l + l16 * 8;
    float4 we0 = *(const float4*)(wer + 0);
    float4 we1 = *(const float4*)(wer + 4);
    float dot = a[0] * we0.x + a[1] * we0.y + a[2] * we0.z + a[3] * we0.w
              + a[4] * we1.x + a[5] * we1.y + a[6] * we1.z + a[7] * we1.w;
    #pragma unroll
    for (int off = 8; off > 0; off >>= 1) dot += __shfl_xor(dot, off);
    if (l16 == 0) energy[n] += (dot + be_l[0]) * temp_l[0];
}

extern "C" void kernel_launch(void* const* d_in, const int* in_sizes, int n_in,
                              void* d_out, int out_size, void* d_ws, size_t ws_size,
                              hipStream_t stream) {
    const float* x    = (const float*)d_in[0];
    const int*   src  = (const int*)d_in[1];
    const int*   dst  = (const int*)d_in[2];
    const float* w    = (const float*)d_in[3];
    const float* Ws   = (const float*)d_in[4];
    const float* bs   = (const float*)d_in[5];
    const float* We   = (const float*)d_in[6];
    const float* be   = (const float*)d_in[7];
    const float* temp = (const float*)d_in[8];

    float* energy = (float*)d_out;            // [N]
    float* xout   = (float*)d_out + N_NODES;  // [N,128] f32 final x
    uint* xb = (uint*)xout;                   // bf16 x0 scratch aliases xout

    // workspace
    ushort* h0     = (ushort*)d_ws;                       // MPAD*128 bf16
    ushort* h1     = h0 + (size_t)MPAD * HIDDEN;          // MPAD*128 bf16
    int2*   epack  = (int2*)(h1 + (size_t)MPAD * HIDDEN); // E (8B each)
    int*    cnt    = (int*)(epack + N_EDGES);
    int*    fillc  = cnt + N_NODES;
    int*    excl   = fillc + N_NODES;
    int*    bsums  = excl + N_NODES;                      // 128
    int*    rowptr = bsums + 128;                         // N+1
    ushort* whi    = (ushort*)(rowptr + N_NODES + 4);     // 4*128*128
    ushort* wlo    = whi + N_LAYERS * HIDDEN * HIDDEN;

    // ---- zero cnt+fillc in one shot ----
    hipMemsetAsync(cnt, 0, 2 * N_NODES * sizeof(int), stream);

    // ---- fused prologue: tap0+cast | count_dst | prep_w ----
    prologue<<<TAP0_BLOCKS + CNT_BLOCKS + PREPW_BLOCKS, 256, 0, stream>>>(
        x, We, be, temp, energy, xb, dst, cnt, Ws, whi, wlo);

    // ---- scan -> rowptr ----
    int nblk = (N_NODES + 1023) / 1024;   // 98
    scan1<<<nblk, 256, 0, stream>>>(cnt, excl, bsums, N_NODES);
    scan23<<<(N_NODES + 1 + 255) / 256, 256, 0, stream>>>(excl, bsums, rowptr, N_NODES, nblk);

    // ---- fused CSR fill + gemm0 (xb -> h0) ----
    fill_gemm0<<<GEMM_BLOCKS + CNT_BLOCKS, 256, 0, stream>>>(
        src, dst, w, rowptr, fillc, epack, xb, whi, wlo, bs, h0);

    // ---- fused agg_i + gemm_{i+1}, h ping-pong ----
    agg_gemm<<<GEMM_BLOCKS, 256, 0, stream>>>(
        h0, rowptr, epack, We + 1 * HIDDEN, be + 1, temp + 1, energy,
        whi + 1 * HIDDEN * HIDDEN, wlo + 1 * HIDDEN * HIDDEN, bs + 1 * HIDDEN, h1);
    agg_gemm<<<GEMM_BLOCKS, 256, 0, stream>>>(
        h1, rowptr, epack, We + 2 * HIDDEN, be + 2, temp + 2, energy,
        whi + 2 * HIDDEN * HIDDEN, wlo + 2 * HIDDEN * HIDDEN, bs + 2 * HIDDEN, h0);
    agg_gemm<<<GEMM_BLOCKS, 256, 0, stream>>>(
        h0, rowptr, epack, We + 3 * HIDDEN, be + 3, temp + 3, energy,
        whi + 3 * HIDDEN * HIDDEN, wlo + 3 * HIDDEN * HIDDEN, bs + 3 * HIDDEN, h1);

    // ---- final agg: relu + tap4 + f32 x ----
    agg_final<<<(N_NODES * 16 + 255) / 256, 256, 0, stream>>>(
        h1, rowptr, epack, We + 4 * HIDDEN, be + 4, temp + 4, xout, energy);
}

// Round 12
// 281.417 us; speedup vs baseline: 1.1041x; 1.0298x over previous
//
#include <hip/hip_runtime.h>
#include <hip/hip_bf16.h>

#define N_NODES 100000
#define N_EDGES 600000
#define HIDDEN 128
#define N_LAYERS 4
#define MPAD 100096   // N_NODES rounded up to 128 (and to 64)
#define CPAD 16       // counter padding: one counter per 64B line

#define TAP0_BLOCKS ((N_NODES * 16) / 256)                       // 6250
#define CNT_BLOCKS ((N_EDGES + 255) / 256)                       // 2344
#define PREPW_BLOCKS ((N_LAYERS * HIDDEN * HIDDEN + 255) / 256)  // 256
#define GEMM_BLOCKS (MPAD / 64)                                  // 1564

typedef short bf16x8 __attribute__((ext_vector_type(8)));
typedef float f32x4 __attribute__((ext_vector_type(4)));
typedef float f32x8 __attribute__((ext_vector_type(8)));

__device__ inline ushort f2bf(float f) {
    __hip_bfloat16 h = __float2bfloat16(f);
    return *reinterpret_cast<ushort*>(&h);
}

__device__ inline float bfhi(uint u) { return __uint_as_float(u << 16); }
__device__ inline float bflo(uint u) { return __uint_as_float(u & 0xffff0000u); }

// Shared gather body (round-8 proven): 16 lanes/node, uint4/lane, exact-width
// 4/2/1 rounds, ONE shared loop body (no degree tiers - round-9 lesson).
#define FMA8(U, P) { float wk = __int_as_float(P.y); \
    a[0] += bfhi(U.x) * wk; a[1] += bflo(U.x) * wk; \
    a[2] += bfhi(U.y) * wk; a[3] += bflo(U.y) * wk; \
    a[4] += bfhi(U.z) * wk; a[5] += bflo(U.z) * wk; \
    a[6] += bfhi(U.w) * wk; a[7] += bflo(U.w) * wk; }

__device__ __forceinline__ void gather_agg(const char* __restrict__ hrow,
                                           const int2* __restrict__ epack,
                                           int j0, int j1, int cb, float* a) {
    int j = j0;
    for (; j + 4 <= j1; j += 4) {
        int2 p0 = epack[j], p1 = epack[j + 1], p2 = epack[j + 2], p3 = epack[j + 3];
        uint4 u0 = *(const uint4*)(hrow + (size_t)p0.x * 256 + cb);
        uint4 u1 = *(const uint4*)(hrow + (size_t)p1.x * 256 + cb);
        uint4 u2 = *(const uint4*)(hrow + (size_t)p2.x * 256 + cb);
        uint4 u3 = *(const uint4*)(hrow + (size_t)p3.x * 256 + cb);
        FMA8(u0, p0); FMA8(u1, p1); FMA8(u2, p2); FMA8(u3, p3);
    }
    if (j + 2 <= j1) {
        int2 p0 = epack[j], p1 = epack[j + 1];
        uint4 u0 = *(const uint4*)(hrow + (size_t)p0.x * 256 + cb);
        uint4 u1 = *(const uint4*)(hrow + (size_t)p1.x * 256 + cb);
        FMA8(u0, p0); FMA8(u1, p1);
        j += 2;
    }
    if (j < j1) {
        int2 p0 = epack[j];
        uint4 u0 = *(const uint4*)(hrow + (size_t)p0.x * 256 + cb);
        FMA8(u0, p0);
    }
}

// ===========================================================================
// Prologue (fused independent prep): tap0+cast x0 | count_dst | prep_w
// cnt is 64B-line padded (round-11 lesson: same-line atomic serialization).
// ===========================================================================
__global__ void prologue(const float* __restrict__ x, const float* __restrict__ We,
                         const float* __restrict__ be, const float* __restrict__ temp,
                         float* __restrict__ energy, uint* __restrict__ xb,
                         const int* __restrict__ dst, int* __restrict__ cnt,
                         const float* __restrict__ Ws, ushort* __restrict__ whi,
                         ushort* __restrict__ wlo) {
    int b = blockIdx.x;
    if (b < TAP0_BLOCKS) {
        int gtid = b * 256 + threadIdx.x;
        int n = gtid >> 4, l16 = gtid & 15;
        f32x8 v = *(const f32x8*)(x + (size_t)n * HIDDEN + l16 * 8);
        uint4 packed;
        packed.x = (uint)f2bf(v[0]) | ((uint)f2bf(v[1]) << 16);
        packed.y = (uint)f2bf(v[2]) | ((uint)f2bf(v[3]) << 16);
        packed.z = (uint)f2bf(v[4]) | ((uint)f2bf(v[5]) << 16);
        packed.w = (uint)f2bf(v[6]) | ((uint)f2bf(v[7]) << 16);
        ((uint4*)(xb + (size_t)n * 64))[l16] = packed;
        f32x8 we = *(const f32x8*)(We + l16 * 8);
        float dot = v[0] * we[0] + v[1] * we[1] + v[2] * we[2] + v[3] * we[3]
                  + v[4] * we[4] + v[5] * we[5] + v[6] * we[6] + v[7] * we[7];
        #pragma unroll
        for (int off = 8; off > 0; off >>= 1) dot += __shfl_xor(dot, off);
        if (l16 == 0) energy[n] = (dot + be[0]) * temp[0];
    } else if (b < TAP0_BLOCKS + CNT_BLOCKS) {
        int e = (b - TAP0_BLOCKS) * 256 + threadIdx.x;
        if (e < N_EDGES) atomicAdd(&cnt[(size_t)dst[e] * CPAD], 1);
    } else {
        int idx = (b - TAP0_BLOCKS - CNT_BLOCKS) * 256 + threadIdx.x;
        if (idx < N_LAYERS * HIDDEN * HIDDEN) {
            int l = idx >> 14;
            int r = idx & 16383;
            int c = r >> 7, k = r & 127;
            float v = Ws[(l << 14) + k * HIDDEN + c];
            ushort hi = f2bf(v);
            float hif = __uint_as_float(((uint)hi) << 16);
            whi[idx] = hi;
            wlo[idx] = f2bf(v - hif);
        }
    }
}

// ===========================================================================
// Exclusive scan over padded cnt -> rowptr (scan1 + merged scan23)
// ===========================================================================
__global__ void scan1(const int* __restrict__ cnt, int* __restrict__ excl,
                      int* __restrict__ bsums, int n) {
    __shared__ int lds[8];
    int t = threadIdx.x;
    int base = blockIdx.x * 1024 + t * 4;
    int v0 = (base + 0 < n) ? cnt[(size_t)(base + 0) * CPAD] : 0;
    int v1 = (base + 1 < n) ? cnt[(size_t)(base + 1) * CPAD] : 0;
    int v2 = (base + 2 < n) ? cnt[(size_t)(base + 2) * CPAD] : 0;
    int v3 = (base + 3 < n) ? cnt[(size_t)(base + 3) * CPAD] : 0;
    int tsum = v0 + v1 + v2 + v3;
    int lane = t & 63, wv = t >> 6;
    int s = tsum;
    #pragma unroll
    for (int off = 1; off < 64; off <<= 1) {
        int u = __shfl_up(s, off);
        if (lane >= off) s += u;
    }
    if (lane == 63) lds[wv] = s;
    __syncthreads();
    if (t == 0) {
        int a = 0;
        #pragma unroll
        for (int i = 0; i < 4; ++i) { int bb = lds[i]; lds[i] = a; a += bb; }
        lds[4] = a;
    }
    __syncthreads();
    int excl_t = (s - tsum) + lds[wv];
    if (base + 0 < n) excl[base + 0] = excl_t;
    if (base + 1 < n) excl[base + 1] = excl_t + v0;
    if (base + 2 < n) excl[base + 2] = excl_t + v0 + v1;
    if (base + 3 < n) excl[base + 3] = excl_t + v0 + v1 + v2;
    if (t == 0) bsums[blockIdx.x] = lds[4];
}

__global__ void scan23(const int* __restrict__ excl, const int* __restrict__ bsums,
                       int* __restrict__ rowptr, int n, int nb) {
    __shared__ int bp[128];
    int t = threadIdx.x;
    if (t < nb) bp[t] = bsums[t];
    __syncthreads();
    if (t == 0) {
        int a = 0;
        for (int i = 0; i < nb; ++i) { int v = bp[i]; bp[i] = a; a += v; }
    }
    __syncthreads();
    int i = blockIdx.x * blockDim.x + t;
    if (i < n) rowptr[i] = excl[i] + bp[i >> 10];
    else if (i == n) rowptr[n] = N_EDGES;
}

// ===========================================================================
// Fused CSR fill + layer-0 GEMM, 3:2 INTERLEAVED block mapping so every CU
// co-hosts latency-bound fill waves and compute-bound gemm waves
// (round-11 lesson: range-split gave zero overlap). fillc is line-padded.
// ===========================================================================
__global__ __launch_bounds__(256) void fill_gemm0(
    const int* __restrict__ src, const int* __restrict__ dst,
    const float* __restrict__ w, const int* __restrict__ rowptr,
    int* __restrict__ fillc, int2* __restrict__ epack,
    const uint* __restrict__ xb,
    const ushort* __restrict__ whi, const ushort* __restrict__ wlo,
    const float* __restrict__ b, ushort* __restrict__ h) {
    int t = threadIdx.x;
    int bm = blockIdx.x % 5;
    if (bm >= 2) {
        // fill block: fid in [0, CNT_BLOCKS)
        int fid = (blockIdx.x / 5) * 3 + (bm - 2);
        int e = fid * 256 + t;
        if (e < N_EDGES) {
            int d = dst[e];
            int pos = atomicAdd(&fillc[(size_t)d * CPAD], 1);
            epack[rowptr[d] + pos] = make_int2(src[e], __float_as_int(w[e]));
        }
        return;
    }
    int gid = (blockIdx.x / 5) * 2 + bm;   // gemm block: gid in [0, GEMM_BLOCKS)

    __shared__ uint4 sx4[1024];          // 16 KB
    char* sxb = (char*)sx4;
    int lane = t & 63, wv = t >> 6;
    int l15 = lane & 15, l4 = lane >> 4;
    int row0 = gid * 64;
    int c0 = wv * 32;

    bf16x8 Ah[2][4], Al[2][4];
    #pragma unroll
    for (int m = 0; m < 2; ++m) {
        int c = c0 + m * 16 + l15;
        #pragma unroll
        for (int s = 0; s < 4; ++s) {
            int off = c * HIDDEN + s * 32 + l4 * 8;
            Ah[m][s] = *(const bf16x8*)(whi + off);
            Al[m][s] = *(const bf16x8*)(wlo + off);
        }
    }

    #pragma unroll
    for (int j = 0; j < 4; ++j) {
        int c = j * 256 + t;
        int row = c >> 4;
        int colb = (c & 15) * 16;
        int grow = row0 + row;
        if (grow >= N_NODES) grow = N_NODES - 1;
        uint4 v = *(const uint4*)((const char*)xb + (size_t)grow * 256 + colb);
        *(uint4*)(sxb + row * 256 + (colb ^ ((row & 7) << 4))) = v;
    }
    __syncthreads();

    f32x4 acc[2][4];
    #pragma unroll
    for (int m = 0; m < 2; ++m)
        #pragma unroll
        for (int n = 0; n < 4; ++n)
            acc[m][n] = f32x4{0.f, 0.f, 0.f, 0.f};

    #pragma unroll
    for (int n = 0; n < 4; ++n) {
        int row = n * 16 + l15;
        int rsw = (row & 7) << 4;
        #pragma unroll
        for (int s = 0; s < 4; ++s) {
            bf16x8 bh = *(const bf16x8*)(sxb + row * 256 + ((s * 64 + l4 * 16) ^ rsw));
            #pragma unroll
            for (int m = 0; m < 2; ++m) {
                acc[m][n] = __builtin_amdgcn_mfma_f32_16x16x32_bf16(Ah[m][s], bh, acc[m][n], 0, 0, 0);
                acc[m][n] = __builtin_amdgcn_mfma_f32_16x16x32_bf16(Al[m][s], bh, acc[m][n], 0, 0, 0);
            }
        }
    }

    #pragma unroll
    for (int m = 0; m < 2; ++m) {
        f32x4 bias = *(const f32x4*)(b + c0 + m * 16 + l4 * 4);
        #pragma unroll
        for (int n = 0; n < 4; ++n) {
            int node = row0 + n * 16 + l15;
            f32x4 r = acc[m][n] + bias;
            uint2 packed;
            packed.x = (uint)f2bf(r[0]) | ((uint)f2bf(r[1]) << 16);
            packed.y = (uint)f2bf(r[2]) | ((uint)f2bf(r[3]) << 16);
            *(uint2*)(h + (size_t)node * HIDDEN + c0 + m * 16 + l4 * 4) = packed;
        }
    }
}

// ===========================================================================
// Fused agg_i + gemm_{i+1}: block owns 64 nodes; phase A aggregates them
// (relu + tap) straight into the swizzled LDS tile, phase B runs the MFMA
// gemm from LDS into h_next. h ping-pongs across layers.
// ===========================================================================
__global__ __launch_bounds__(256) void agg_gemm(
    const ushort* __restrict__ hprev, const int* __restrict__ rowptr,
    const int2* __restrict__ epack,
    const float* __restrict__ We_l, const float* __restrict__ be_l,
    const float* __restrict__ temp_l, float* __restrict__ energy,
    const ushort* __restrict__ whi, const ushort* __restrict__ wlo,
    const float* __restrict__ b, ushort* __restrict__ hnext) {
    __shared__ uint4 sx4[1024];          // 16 KB
    char* sxb = (char*)sx4;
    int t = threadIdx.x;
    int row0 = blockIdx.x * 64;
    int g = t >> 4, l16 = t & 15;
    int cb = l16 * 16;
    const char* hrow = (const char*)hprev;

    // ---- phase A: aggregate 64 nodes (16 groups x 4 passes) ----
    #pragma unroll 1
    for (int p = 0; p < 4; ++p) {
        int n = row0 + p * 16 + g;
        float a[8] = {0.f, 0.f, 0.f, 0.f, 0.f, 0.f, 0.f, 0.f};
        if (n < N_NODES) {
            int j0 = rowptr[n], j1 = rowptr[n + 1];
            gather_agg(hrow, epack, j0, j1, cb, a);
            #pragma unroll
            for (int q = 0; q < 8; ++q) a[q] = a[q] > 0.f ? a[q] : 0.01f * a[q];
            const float* wer = We_l + l16 * 8;
            float4 we0 = *(const float4*)(wer + 0);
            float4 we1 = *(const float4*)(wer + 4);
            float dot = a[0] * we0.x + a[1] * we0.y + a[2] * we0.z + a[3] * we0.w
                      + a[4] * we1.x + a[5] * we1.y + a[6] * we1.z + a[7] * we1.w;
            #pragma unroll
            for (int off = 8; off > 0; off >>= 1) dot += __shfl_xor(dot, off);
            if (l16 == 0) energy[n] += (dot + be_l[0]) * temp_l[0];
        }
        uint4 packed;
        packed.x = (uint)f2bf(a[0]) | ((uint)f2bf(a[1]) << 16);
        packed.y = (uint)f2bf(a[2]) | ((uint)f2bf(a[3]) << 16);
        packed.z = (uint)f2bf(a[4]) | ((uint)f2bf(a[5]) << 16);
        packed.w = (uint)f2bf(a[6]) | ((uint)f2bf(a[7]) << 16);
        int r = p * 16 + g;
        *(uint4*)(sxb + r * 256 + (cb ^ ((r & 7) << 4))) = packed;
    }

    // ---- phase B: gemm from LDS ----
    int lane = t & 63, wv = t >> 6;
    int l15 = lane & 15, l4 = lane >> 4;
    int c0 = wv * 32;
    bf16x8 Ah[2][4], Al[2][4];
    #pragma unroll
    for (int m = 0; m < 2; ++m) {
        int c = c0 + m * 16 + l15;
        #pragma unroll
        for (int s = 0; s < 4; ++s) {
            int off = c * HIDDEN + s * 32 + l4 * 8;
            Ah[m][s] = *(const bf16x8*)(whi + off);
            Al[m][s] = *(const bf16x8*)(wlo + off);
        }
    }
    __syncthreads();

    f32x4 acc[2][4];
    #pragma unroll
    for (int m = 0; m < 2; ++m)
        #pragma unroll
        for (int n = 0; n < 4; ++n)
            acc[m][n] = f32x4{0.f, 0.f, 0.f, 0.f};

    #pragma unroll
    for (int n = 0; n < 4; ++n) {
        int row = n * 16 + l15;
        int rsw = (row & 7) << 4;
        #pragma unroll
        for (int s = 0; s < 4; ++s) {
            bf16x8 bh = *(const bf16x8*)(sxb + row * 256 + ((s * 64 + l4 * 16) ^ rsw));
            #pragma unroll
            for (int m = 0; m < 2; ++m) {
                acc[m][n] = __builtin_amdgcn_mfma_f32_16x16x32_bf16(Ah[m][s], bh, acc[m][n], 0, 0, 0);
                acc[m][n] = __builtin_amdgcn_mfma_f32_16x16x32_bf16(Al[m][s], bh, acc[m][n], 0, 0, 0);
            }
        }
    }

    #pragma unroll
    for (int m = 0; m < 2; ++m) {
        f32x4 bias = *(const f32x4*)(b + c0 + m * 16 + l4 * 4);
        #pragma unroll
        for (int n = 0; n < 4; ++n) {
            int node = row0 + n * 16 + l15;
            f32x4 r = acc[m][n] + bias;
            uint2 packed;
            packed.x = (uint)f2bf(r[0]) | ((uint)f2bf(r[1]) << 16);
            packed.y = (uint)f2bf(r[2]) | ((uint)f2bf(r[3]) << 16);
            *(uint2*)(hnext + (size_t)node * HIDDEN + c0 + m * 16 + l4 * 4) = packed;
        }
    }
}

// ===========================================================================
// Final aggregation: relu + tap4 + f32 x out.
// ===========================================================================
__global__ void agg_final(const ushort* __restrict__ h, const int* __restrict__ rowptr,
                          const int2* __restrict__ epack,
                          const float* __restrict__ We_l, const float* __restrict__ be_l,
                          const float* __restrict__ temp_l,
                          float* __restrict__ xout, float* __restrict__ energy) {
    int gtid = blockIdx.x * blockDim.x + threadIdx.x;
    int n = gtid >> 4;
    int l16 = gtid & 15;
    if (n >= N_NODES) return;
    int j0 = rowptr[n], j1 = rowptr[n + 1];
    int cb = l16 * 16;
    float a[8] = {0.f, 0.f, 0.f, 0.f, 0.f, 0.f, 0.f, 0.f};
    gather_agg((const char*)h, epack, j0, j1, cb, a);
    #pragma unroll
    for (int q = 0; q < 8; ++q) a[q] = a[q] > 0.f ? a[q] : 0.01f * a[q];

    float* orow = xout + (size_t)n * HIDDEN + l16 * 8;
    *(float4*)(orow + 0) = float4{a[0], a[1], a[2], a[3]};
    *(float4*)(orow + 4) = float4{a[4], a[5], a[6], a[7]};

    const float* wer = We_l + l16 * 8;
    float4 we0 = *(const float4*)(wer + 0);
    float4 we1 = *(const float4*)(wer + 4);
    float dot = a[0] * we0.x + a[1] * we0.y + a[2] * we0.z + a[3] * we0.w
              + a[4] * we1.x + a[5] * we1.y + a[6] * we1.z + a[7] * we1.w;
    #pragma unroll
    for (int off = 8; off > 0; off >>= 1) dot += __shfl_xor(dot, off);
    if (l16 == 0) energy[n] += (dot + be_l[0]) * temp_l[0];
}

extern "C" void kernel_launch(void* const* d_in, const int* in_sizes, int n_in,
                              void* d_out, int out_size, void* d_ws, size_t ws_size,
                              hipStream_t stream) {
    const float* x    = (const float*)d_in[0];
    const int*   src  = (const int*)d_in[1];
    const int*   dst  = (const int*)d_in[2];
    const float* w    = (const float*)d_in[3];
    const float* Ws   = (const float*)d_in[4];
    const float* bs   = (const float*)d_in[5];
    const float* We   = (const float*)d_in[6];
    const float* be   = (const float*)d_in[7];
    const float* temp = (const float*)d_in[8];

    float* energy = (float*)d_out;            // [N]
    float* xout   = (float*)d_out + N_NODES;  // [N,128] f32 final x
    uint* xb = (uint*)xout;                   // bf16 x0 scratch aliases xout

    // workspace
    ushort* h0     = (ushort*)d_ws;                       // MPAD*128 bf16
    ushort* h1     = h0 + (size_t)MPAD * HIDDEN;          // MPAD*128 bf16
    int2*   epack  = (int2*)(h1 + (size_t)MPAD * HIDDEN); // E (8B each)
    int*    cnt    = (int*)(epack + N_EDGES);             // N*CPAD (padded)
    int*    fillc  = cnt + (size_t)N_NODES * CPAD;        // N*CPAD (padded)
    int*    excl   = fillc + (size_t)N_NODES * CPAD;
    int*    bsums  = excl + N_NODES;                      // 128
    int*    rowptr = bsums + 128;                         // N+1
    ushort* whi    = (ushort*)(rowptr + N_NODES + 4);     // 4*128*128
    ushort* wlo    = whi + N_LAYERS * HIDDEN * HIDDEN;

    // ---- zero padded cnt+fillc in one shot (12.8MB) ----
    hipMemsetAsync(cnt, 0, 2 * (size_t)N_NODES * CPAD * sizeof(int), stream);

    // ---- fused prologue: tap0+cast | count_dst | prep_w ----
    prologue<<<TAP0_BLOCKS + CNT_BLOCKS + PREPW_BLOCKS, 256, 0, stream>>>(
        x, We, be, temp, energy, xb, dst, cnt, Ws, whi, wlo);

    // ---- scan -> rowptr ----
    int nblk = (N_NODES + 1023) / 1024;   // 98
    scan1<<<nblk, 256, 0, stream>>>(cnt, excl, bsums, N_NODES);
    scan23<<<(N_NODES + 1 + 255) / 256, 256, 0, stream>>>(excl, bsums, rowptr, N_NODES, nblk);

    // ---- fused CSR fill + gemm0 (3:2 interleaved) ----
    fill_gemm0<<<GEMM_BLOCKS + CNT_BLOCKS, 256, 0, stream>>>(
        src, dst, w, rowptr, fillc, epack, xb, whi, wlo, bs, h0);

    // ---- fused agg_i + gemm_{i+1}, h ping-pong ----
    agg_gemm<<<GEMM_BLOCKS, 256, 0, stream>>>(
        h0, rowptr, epack, We + 1 * HIDDEN, be + 1, temp + 1, energy,
        whi + 1 * HIDDEN * HIDDEN, wlo + 1 * HIDDEN * HIDDEN, bs + 1 * HIDDEN, h1);
    agg_gemm<<<GEMM_BLOCKS, 256, 0, stream>>>(
        h1, rowptr, epack, We + 2 * HIDDEN, be + 2, temp + 2, energy,
        whi + 2 * HIDDEN * HIDDEN, wlo + 2 * HIDDEN * HIDDEN, bs + 2 * HIDDEN, h0);
    agg_gemm<<<GEMM_BLOCKS, 256, 0, stream>>>(
        h0, rowptr, epack, We + 3 * HIDDEN, be + 3, temp + 3, energy,
        whi + 3 * HIDDEN * HIDDEN, wlo + 3 * HIDDEN * HIDDEN, bs + 3 * HIDDEN, h1);

    // ---- final agg: relu + tap4 + f32 x ----
    agg_final<<<(N_NODES * 16 + 255) / 256, 256, 0, stream>>>(
        h1, rowptr, epack, We + 4 * HIDDEN, be + 4, temp + 4, xout, energy);
}

// Round 13
// 277.671 us; speedup vs baseline: 1.1190x; 1.0135x over previous
//
#include <hip/hip_runtime.h>
#include <hip/hip_bf16.h>

#define N_NODES 100000
#define N_EDGES 600000
#define HIDDEN 128
#define N_LAYERS 4
#define MPAD 100096   // N_NODES rounded up to 128 (and to 64)
#define CPAD 16       // counter padding: one counter per 64B line

#define TAP0_BLOCKS ((N_NODES * 16) / 256)                       // 6250
#define CNT_BLOCKS ((N_EDGES + 255) / 256)                       // 2344
#define PREPW_BLOCKS ((N_LAYERS * HIDDEN * HIDDEN + 255) / 256)  // 256
#define GEMM_BLOCKS (MPAD / 64)                                  // 1564

typedef short bf16x8 __attribute__((ext_vector_type(8)));
typedef float f32x4 __attribute__((ext_vector_type(4)));
typedef float f32x8 __attribute__((ext_vector_type(8)));

__device__ inline ushort f2bf(float f) {
    __hip_bfloat16 h = __float2bfloat16(f);
    return *reinterpret_cast<ushort*>(&h);
}

__device__ inline float bfhi(uint u) { return __uint_as_float(u << 16); }
__device__ inline float bflo(uint u) { return __uint_as_float(u & 0xffff0000u); }

// Shared gather body (round-8 proven): 16 lanes/node, uint4/lane, exact-width
// 4/2/1 rounds, ONE shared loop body (no degree tiers - round-9 lesson).
#define FMA8(U, P) { float wk = __int_as_float(P.y); \
    a[0] += bfhi(U.x) * wk; a[1] += bflo(U.x) * wk; \
    a[2] += bfhi(U.y) * wk; a[3] += bflo(U.y) * wk; \
    a[4] += bfhi(U.z) * wk; a[5] += bflo(U.z) * wk; \
    a[6] += bfhi(U.w) * wk; a[7] += bflo(U.w) * wk; }

__device__ __forceinline__ void gather_agg(const char* __restrict__ hrow,
                                           const int2* __restrict__ epack,
                                           int j0, int j1, int cb, float* a) {
    int j = j0;
    for (; j + 4 <= j1; j += 4) {
        int2 p0 = epack[j], p1 = epack[j + 1], p2 = epack[j + 2], p3 = epack[j + 3];
        uint4 u0 = *(const uint4*)(hrow + (size_t)p0.x * 256 + cb);
        uint4 u1 = *(const uint4*)(hrow + (size_t)p1.x * 256 + cb);
        uint4 u2 = *(const uint4*)(hrow + (size_t)p2.x * 256 + cb);
        uint4 u3 = *(const uint4*)(hrow + (size_t)p3.x * 256 + cb);
        FMA8(u0, p0); FMA8(u1, p1); FMA8(u2, p2); FMA8(u3, p3);
    }
    if (j + 2 <= j1) {
        int2 p0 = epack[j], p1 = epack[j + 1];
        uint4 u0 = *(const uint4*)(hrow + (size_t)p0.x * 256 + cb);
        uint4 u1 = *(const uint4*)(hrow + (size_t)p1.x * 256 + cb);
        FMA8(u0, p0); FMA8(u1, p1);
        j += 2;
    }
    if (j < j1) {
        int2 p0 = epack[j];
        uint4 u0 = *(const uint4*)(hrow + (size_t)p0.x * 256 + cb);
        FMA8(u0, p0);
    }
}

// ===========================================================================
// Prologue (fused independent prep): tap0+cast x0 | count_dst | prep_w
// count phase ALSO records each edge's slot-within-bucket (eslot) so the
// fill phase needs NO atomics (round-12 lesson: the atomic-with-return
// round-trip was the fill serializer, and we were paying it twice).
// ===========================================================================
__global__ void prologue(const float* __restrict__ x, const float* __restrict__ We,
                         const float* __restrict__ be, const float* __restrict__ temp,
                         float* __restrict__ energy, uint* __restrict__ xb,
                         const int* __restrict__ dst, int* __restrict__ cnt,
                         int* __restrict__ eslot,
                         const float* __restrict__ Ws, ushort* __restrict__ whi,
                         ushort* __restrict__ wlo) {
    int b = blockIdx.x;
    if (b < TAP0_BLOCKS) {
        int gtid = b * 256 + threadIdx.x;
        int n = gtid >> 4, l16 = gtid & 15;
        f32x8 v = *(const f32x8*)(x + (size_t)n * HIDDEN + l16 * 8);
        uint4 packed;
        packed.x = (uint)f2bf(v[0]) | ((uint)f2bf(v[1]) << 16);
        packed.y = (uint)f2bf(v[2]) | ((uint)f2bf(v[3]) << 16);
        packed.z = (uint)f2bf(v[4]) | ((uint)f2bf(v[5]) << 16);
        packed.w = (uint)f2bf(v[6]) | ((uint)f2bf(v[7]) << 16);
        ((uint4*)(xb + (size_t)n * 64))[l16] = packed;
        f32x8 we = *(const f32x8*)(We + l16 * 8);
        float dot = v[0] * we[0] + v[1] * we[1] + v[2] * we[2] + v[3] * we[3]
                  + v[4] * we[4] + v[5] * we[5] + v[6] * we[6] + v[7] * we[7];
        #pragma unroll
        for (int off = 8; off > 0; off >>= 1) dot += __shfl_xor(dot, off);
        if (l16 == 0) energy[n] = (dot + be[0]) * temp[0];
    } else if (b < TAP0_BLOCKS + CNT_BLOCKS) {
        int e = (b - TAP0_BLOCKS) * 256 + threadIdx.x;
        if (e < N_EDGES)
            eslot[e] = atomicAdd(&cnt[(size_t)dst[e] * CPAD], 1);
    } else {
        int idx = (b - TAP0_BLOCKS - CNT_BLOCKS) * 256 + threadIdx.x;
        if (idx < N_LAYERS * HIDDEN * HIDDEN) {
            int l = idx >> 14;
            int r = idx & 16383;
            int c = r >> 7, k = r & 127;
            float v = Ws[(l << 14) + k * HIDDEN + c];
            ushort hi = f2bf(v);
            float hif = __uint_as_float(((uint)hi) << 16);
            whi[idx] = hi;
            wlo[idx] = f2bf(v - hif);
        }
    }
}

// ===========================================================================
// Exclusive scan over padded cnt -> rowptr (scan1 + merged scan23)
// ===========================================================================
__global__ void scan1(const int* __restrict__ cnt, int* __restrict__ excl,
                      int* __restrict__ bsums, int n) {
    __shared__ int lds[8];
    int t = threadIdx.x;
    int base = blockIdx.x * 1024 + t * 4;
    int v0 = (base + 0 < n) ? cnt[(size_t)(base + 0) * CPAD] : 0;
    int v1 = (base + 1 < n) ? cnt[(size_t)(base + 1) * CPAD] : 0;
    int v2 = (base + 2 < n) ? cnt[(size_t)(base + 2) * CPAD] : 0;
    int v3 = (base + 3 < n) ? cnt[(size_t)(base + 3) * CPAD] : 0;
    int tsum = v0 + v1 + v2 + v3;
    int lane = t & 63, wv = t >> 6;
    int s = tsum;
    #pragma unroll
    for (int off = 1; off < 64; off <<= 1) {
        int u = __shfl_up(s, off);
        if (lane >= off) s += u;
    }
    if (lane == 63) lds[wv] = s;
    __syncthreads();
    if (t == 0) {
        int a = 0;
        #pragma unroll
        for (int i = 0; i < 4; ++i) { int bb = lds[i]; lds[i] = a; a += bb; }
        lds[4] = a;
    }
    __syncthreads();
    int excl_t = (s - tsum) + lds[wv];
    if (base + 0 < n) excl[base + 0] = excl_t;
    if (base + 1 < n) excl[base + 1] = excl_t + v0;
    if (base + 2 < n) excl[base + 2] = excl_t + v0 + v1;
    if (base + 3 < n) excl[base + 3] = excl_t + v0 + v1 + v2;
    if (t == 0) bsums[blockIdx.x] = lds[4];
}

__global__ void scan23(const int* __restrict__ excl, const int* __restrict__ bsums,
                       int* __restrict__ rowptr, int n, int nb) {
    __shared__ int bp[128];
    int t = threadIdx.x;
    if (t < nb) bp[t] = bsums[t];
    __syncthreads();
    if (t == 0) {
        int a = 0;
        for (int i = 0; i < nb; ++i) { int v = bp[i]; bp[i] = a; a += v; }
    }
    __syncthreads();
    int i = blockIdx.x * blockDim.x + t;
    if (i < n) rowptr[i] = excl[i] + bp[i >> 10];
    else if (i == n) rowptr[n] = N_EDGES;
}

// ===========================================================================
// Fused CSR fill + layer-0 GEMM, 3:2 interleaved. Fill is now ATOMIC-FREE:
// slot = rowptr[dst[e]] + eslot[e] (precomputed in prologue's count phase).
// ===========================================================================
__global__ __launch_bounds__(256) void fill_gemm0(
    const int* __restrict__ src, const int* __restrict__ dst,
    const float* __restrict__ w, const int* __restrict__ rowptr,
    const int* __restrict__ eslot, int2* __restrict__ epack,
    const uint* __restrict__ xb,
    const ushort* __restrict__ whi, const ushort* __restrict__ wlo,
    const float* __restrict__ b, ushort* __restrict__ h) {
    int t = threadIdx.x;
    int bm = blockIdx.x % 5;
    if (bm >= 2) {
        // fill block: fid in [0, CNT_BLOCKS)
        int fid = (blockIdx.x / 5) * 3 + (bm - 2);
        int e = fid * 256 + t;
        if (e < N_EDGES) {
            int d = dst[e];
            epack[rowptr[d] + eslot[e]] = make_int2(src[e], __float_as_int(w[e]));
        }
        return;
    }
    int gid = (blockIdx.x / 5) * 2 + bm;   // gemm block: gid in [0, GEMM_BLOCKS)

    __shared__ uint4 sx4[1024];          // 16 KB
    char* sxb = (char*)sx4;
    int lane = t & 63, wv = t >> 6;
    int l15 = lane & 15, l4 = lane >> 4;
    int row0 = gid * 64;
    int c0 = wv * 32;

    bf16x8 Ah[2][4], Al[2][4];
    #pragma unroll
    for (int m = 0; m < 2; ++m) {
        int c = c0 + m * 16 + l15;
        #pragma unroll
        for (int s = 0; s < 4; ++s) {
            int off = c * HIDDEN + s * 32 + l4 * 8;
            Ah[m][s] = *(const bf16x8*)(whi + off);
            Al[m][s] = *(const bf16x8*)(wlo + off);
        }
    }

    #pragma unroll
    for (int j = 0; j < 4; ++j) {
        int c = j * 256 + t;
        int row = c >> 4;
        int colb = (c & 15) * 16;
        int grow = row0 + row;
        if (grow >= N_NODES) grow = N_NODES - 1;
        uint4 v = *(const uint4*)((const char*)xb + (size_t)grow * 256 + colb);
        *(uint4*)(sxb + row * 256 + (colb ^ ((row & 7) << 4))) = v;
    }
    __syncthreads();

    f32x4 acc[2][4];
    #pragma unroll
    for (int m = 0; m < 2; ++m)
        #pragma unroll
        for (int n = 0; n < 4; ++n)
            acc[m][n] = f32x4{0.f, 0.f, 0.f, 0.f};

    #pragma unroll
    for (int n = 0; n < 4; ++n) {
        int row = n * 16 + l15;
        int rsw = (row & 7) << 4;
        #pragma unroll
        for (int s = 0; s < 4; ++s) {
            bf16x8 bh = *(const bf16x8*)(sxb + row * 256 + ((s * 64 + l4 * 16) ^ rsw));
            #pragma unroll
            for (int m = 0; m < 2; ++m) {
                acc[m][n] = __builtin_amdgcn_mfma_f32_16x16x32_bf16(Ah[m][s], bh, acc[m][n], 0, 0, 0);
                acc[m][n] = __builtin_amdgcn_mfma_f32_16x16x32_bf16(Al[m][s], bh, acc[m][n], 0, 0, 0);
            }
        }
    }

    #pragma unroll
    for (int m = 0; m < 2; ++m) {
        f32x4 bias = *(const f32x4*)(b + c0 + m * 16 + l4 * 4);
        #pragma unroll
        for (int n = 0; n < 4; ++n) {
            int node = row0 + n * 16 + l15;
            f32x4 r = acc[m][n] + bias;
            uint2 packed;
            packed.x = (uint)f2bf(r[0]) | ((uint)f2bf(r[1]) << 16);
            packed.y = (uint)f2bf(r[2]) | ((uint)f2bf(r[3]) << 16);
            *(uint2*)(h + (size_t)node * HIDDEN + c0 + m * 16 + l4 * 4) = packed;
        }
    }
}

// ===========================================================================
// Fused agg_i + gemm_{i+1}: block owns 64 nodes; phase A aggregates them
// (relu + tap) straight into the swizzled LDS tile, phase B runs the MFMA
// gemm from LDS into h_next. h ping-pongs across layers.
// ===========================================================================
__global__ __launch_bounds__(256) void agg_gemm(
    const ushort* __restrict__ hprev, const int* __restrict__ rowptr,
    const int2* __restrict__ epack,
    const float* __restrict__ We_l, const float* __restrict__ be_l,
    const float* __restrict__ temp_l, float* __restrict__ energy,
    const ushort* __restrict__ whi, const ushort* __restrict__ wlo,
    const float* __restrict__ b, ushort* __restrict__ hnext) {
    __shared__ uint4 sx4[1024];          // 16 KB
    char* sxb = (char*)sx4;
    int t = threadIdx.x;
    int row0 = blockIdx.x * 64;
    int g = t >> 4, l16 = t & 15;
    int cb = l16 * 16;
    const char* hrow = (const char*)hprev;

    // ---- phase A: aggregate 64 nodes (16 groups x 4 passes) ----
    #pragma unroll 1
    for (int p = 0; p < 4; ++p) {
        int n = row0 + p * 16 + g;
        float a[8] = {0.f, 0.f, 0.f, 0.f, 0.f, 0.f, 0.f, 0.f};
        if (n < N_NODES) {
            int j0 = rowptr[n], j1 = rowptr[n + 1];
            gather_agg(hrow, epack, j0, j1, cb, a);
            #pragma unroll
            for (int q = 0; q < 8; ++q) a[q] = a[q] > 0.f ? a[q] : 0.01f * a[q];
            const float* wer = We_l + l16 * 8;
            float4 we0 = *(const float4*)(wer + 0);
            float4 we1 = *(const float4*)(wer + 4);
            float dot = a[0] * we0.x + a[1] * we0.y + a[2] * we0.z + a[3] * we0.w
                      + a[4] * we1.x + a[5] * we1.y + a[6] * we1.z + a[7] * we1.w;
            #pragma unroll
            for (int off = 8; off > 0; off >>= 1) dot += __shfl_xor(dot, off);
            if (l16 == 0) energy[n] += (dot + be_l[0]) * temp_l[0];
        }
        uint4 packed;
        packed.x = (uint)f2bf(a[0]) | ((uint)f2bf(a[1]) << 16);
        packed.y = (uint)f2bf(a[2]) | ((uint)f2bf(a[3]) << 16);
        packed.z = (uint)f2bf(a[4]) | ((uint)f2bf(a[5]) << 16);
        packed.w = (uint)f2bf(a[6]) | ((uint)f2bf(a[7]) << 16);
        int r = p * 16 + g;
        *(uint4*)(sxb + r * 256 + (cb ^ ((r & 7) << 4))) = packed;
    }

    // ---- phase B: gemm from LDS ----
    int lane = t & 63, wv = t >> 6;
    int l15 = lane & 15, l4 = lane >> 4;
    int c0 = wv * 32;
    bf16x8 Ah[2][4], Al[2][4];
    #pragma unroll
    for (int m = 0; m < 2; ++m) {
        int c = c0 + m * 16 + l15;
        #pragma unroll
        for (int s = 0; s < 4; ++s) {
            int off = c * HIDDEN + s * 32 + l4 * 8;
            Ah[m][s] = *(const bf16x8*)(whi + off);
            Al[m][s] = *(const bf16x8*)(wlo + off);
        }
    }
    __syncthreads();

    f32x4 acc[2][4];
    #pragma unroll
    for (int m = 0; m < 2; ++m)
        #pragma unroll
        for (int n = 0; n < 4; ++n)
            acc[m][n] = f32x4{0.f, 0.f, 0.f, 0.f};

    #pragma unroll
    for (int n = 0; n < 4; ++n) {
        int row = n * 16 + l15;
        int rsw = (row & 7) << 4;
        #pragma unroll
        for (int s = 0; s < 4; ++s) {
            bf16x8 bh = *(const bf16x8*)(sxb + row * 256 + ((s * 64 + l4 * 16) ^ rsw));
            #pragma unroll
            for (int m = 0; m < 2; ++m) {
                acc[m][n] = __builtin_amdgcn_mfma_f32_16x16x32_bf16(Ah[m][s], bh, acc[m][n], 0, 0, 0);
                acc[m][n] = __builtin_amdgcn_mfma_f32_16x16x32_bf16(Al[m][s], bh, acc[m][n], 0, 0, 0);
            }
        }
    }

    #pragma unroll
    for (int m = 0; m < 2; ++m) {
        f32x4 bias = *(const f32x4*)(b + c0 + m * 16 + l4 * 4);
        #pragma unroll
        for (int n = 0; n < 4; ++n) {
            int node = row0 + n * 16 + l15;
            f32x4 r = acc[m][n] + bias;
            uint2 packed;
            packed.x = (uint)f2bf(r[0]) | ((uint)f2bf(r[1]) << 16);
            packed.y = (uint)f2bf(r[2]) | ((uint)f2bf(r[3]) << 16);
            *(uint2*)(hnext + (size_t)node * HIDDEN + c0 + m * 16 + l4 * 4) = packed;
        }
    }
}

// ===========================================================================
// Final aggregation: relu + tap4 + f32 x out.
// ===========================================================================
__global__ void agg_final(const ushort* __restrict__ h, const int* __restrict__ rowptr,
                          const int2* __restrict__ epack,
                          const float* __restrict__ We_l, const float* __restrict__ be_l,
                          const float* __restrict__ temp_l,
                          float* __restrict__ xout, float* __restrict__ energy) {
    int gtid = blockIdx.x * blockDim.x + threadIdx.x;
    int n = gtid >> 4;
    int l16 = gtid & 15;
    if (n >= N_NODES) return;
    int j0 = rowptr[n], j1 = rowptr[n + 1];
    int cb = l16 * 16;
    float a[8] = {0.f, 0.f, 0.f, 0.f, 0.f, 0.f, 0.f, 0.f};
    gather_agg((const char*)h, epack, j0, j1, cb, a);
    #pragma unroll
    for (int q = 0; q < 8; ++q) a[q] = a[q] > 0.f ? a[q] : 0.01f * a[q];

    float* orow = xout + (size_t)n * HIDDEN + l16 * 8;
    *(float4*)(orow + 0) = float4{a[0], a[1], a[2], a[3]};
    *(float4*)(orow + 4) = float4{a[4], a[5], a[6], a[7]};

    const float* wer = We_l + l16 * 8;
    float4 we0 = *(const float4*)(wer + 0);
    float4 we1 = *(const float4*)(wer + 4);
    float dot = a[0] * we0.x + a[1] * we0.y + a[2] * we0.z + a[3] * we0.w
              + a[4] * we1.x + a[5] * we1.y + a[6] * we1.z + a[7] * we1.w;
    #pragma unroll
    for (int off = 8; off > 0; off >>= 1) dot += __shfl_xor(dot, off);
    if (l16 == 0) energy[n] += (dot + be_l[0]) * temp_l[0];
}

extern "C" void kernel_launch(void* const* d_in, const int* in_sizes, int n_in,
                              void* d_out, int out_size, void* d_ws, size_t ws_size,
                              hipStream_t stream) {
    const float* x    = (const float*)d_in[0];
    const int*   src  = (const int*)d_in[1];
    const int*   dst  = (const int*)d_in[2];
    const float* w    = (const float*)d_in[3];
    const float* Ws   = (const float*)d_in[4];
    const float* bs   = (const float*)d_in[5];
    const float* We   = (const float*)d_in[6];
    const float* be   = (const float*)d_in[7];
    const float* temp = (const float*)d_in[8];

    float* energy = (float*)d_out;            // [N]
    float* xout   = (float*)d_out + N_NODES;  // [N,128] f32 final x
    uint* xb = (uint*)xout;                   // bf16 x0 scratch aliases xout

    // workspace
    ushort* h0     = (ushort*)d_ws;                       // MPAD*128 bf16
    ushort* h1     = h0 + (size_t)MPAD * HIDDEN;          // MPAD*128 bf16
    int2*   epack  = (int2*)(h1 + (size_t)MPAD * HIDDEN); // E (8B each)
    int*    cnt    = (int*)(epack + N_EDGES);             // N*CPAD (padded)
    int*    eslot  = cnt + (size_t)N_NODES * CPAD;        // E
    int*    excl   = eslot + N_EDGES;
    int*    bsums  = excl + N_NODES;                      // 128
    int*    rowptr = bsums + 128;                         // N+1
    ushort* whi    = (ushort*)(rowptr + N_NODES + 4);     // 4*128*128
    ushort* wlo    = whi + N_LAYERS * HIDDEN * HIDDEN;

    // ---- zero padded cnt (6.4MB) ----
    hipMemsetAsync(cnt, 0, (size_t)N_NODES * CPAD * sizeof(int), stream);

    // ---- fused prologue: tap0+cast | count_dst(+eslot) | prep_w ----
    prologue<<<TAP0_BLOCKS + CNT_BLOCKS + PREPW_BLOCKS, 256, 0, stream>>>(
        x, We, be, temp, energy, xb, dst, cnt, eslot, Ws, whi, wlo);

    // ---- scan -> rowptr ----
    int nblk = (N_NODES + 1023) / 1024;   // 98
    scan1<<<nblk, 256, 0, stream>>>(cnt, excl, bsums, N_NODES);
    scan23<<<(N_NODES + 1 + 255) / 256, 256, 0, stream>>>(excl, bsums, rowptr, N_NODES, nblk);

    // ---- fused CSR fill (atomic-free) + gemm0 (3:2 interleaved) ----
    fill_gemm0<<<GEMM_BLOCKS + CNT_BLOCKS, 256, 0, stream>>>(
        src, dst, w, rowptr, eslot, epack, xb, whi, wlo, bs, h0);

    // ---- fused agg_i + gemm_{i+1}, h ping-pong ----
    agg_gemm<<<GEMM_BLOCKS, 256, 0, stream>>>(
        h0, rowptr, epack, We + 1 * HIDDEN, be + 1, temp + 1, energy,
        whi + 1 * HIDDEN * HIDDEN, wlo + 1 * HIDDEN * HIDDEN, bs + 1 * HIDDEN, h1);
    agg_gemm<<<GEMM_BLOCKS, 256, 0, stream>>>(
        h1, rowptr, epack, We + 2 * HIDDEN, be + 2, temp + 2, energy,
        whi + 2 * HIDDEN * HIDDEN, wlo + 2 * HIDDEN * HIDDEN, bs + 2 * HIDDEN, h0);
    agg_gemm<<<GEMM_BLOCKS, 256, 0, stream>>>(
        h0, rowptr, epack, We + 3 * HIDDEN, be + 3, temp + 3, energy,
        whi + 3 * HIDDEN * HIDDEN, wlo + 3 * HIDDEN * HIDDEN, bs + 3 * HIDDEN, h1);

    // ---- final agg: relu + tap4 + f32 x ----
    agg_final<<<(N_NODES * 16 + 255) / 256, 256, 0, stream>>>(
        h1, rowptr, epack, We + 4 * HIDDEN, be + 4, temp + 4, xout, energy);
}

// Round 14
// 265.934 us; speedup vs baseline: 1.1684x; 1.0441x over previous
//
#include <hip/hip_runtime.h>
#include <hip/hip_bf16.h>

#define N_NODES 100000
#define N_EDGES 600000
#define HIDDEN 128
#define N_LAYERS 4
#define MPAD 100096   // N_NODES rounded up to 128 (and to 64)
#define CPAD 16       // counter padding: one counter per 64B line

#define TAP0_BLOCKS ((N_NODES * 16) / 256)                       // 6250
#define CNT_BLOCKS ((N_EDGES + 255) / 256)                       // 2344
#define PREPW_BLOCKS ((N_LAYERS * HIDDEN * HIDDEN + 255) / 256)  // 256
#define GEMM_BLOCKS (MPAD / 64)                                  // 1564

typedef short bf16x8 __attribute__((ext_vector_type(8)));
typedef float f32x4 __attribute__((ext_vector_type(4)));
typedef float f32x8 __attribute__((ext_vector_type(8)));

__device__ inline ushort f2bf(float f) {
    __hip_bfloat16 h = __float2bfloat16(f);
    return *reinterpret_cast<ushort*>(&h);
}

__device__ inline float bfhi(uint u) { return __uint_as_float(u << 16); }
__device__ inline float bflo(uint u) { return __uint_as_float(u & 0xffff0000u); }

// Shared gather body (round-8 proven): 16 lanes/node, uint4/lane, exact-width
// 4/2/1 rounds, ONE shared loop body (no degree tiers - round-9 lesson).
#define FMA8(U, P) { float wk = __int_as_float(P.y); \
    a[0] += bfhi(U.x) * wk; a[1] += bflo(U.x) * wk; \
    a[2] += bfhi(U.y) * wk; a[3] += bflo(U.y) * wk; \
    a[4] += bfhi(U.z) * wk; a[5] += bflo(U.z) * wk; \
    a[6] += bfhi(U.w) * wk; a[7] += bflo(U.w) * wk; }

__device__ __forceinline__ void gather_agg(const char* __restrict__ hrow,
                                           const int2* __restrict__ epack,
                                           int j0, int j1, int cb, float* a) {
    int j = j0;
    for (; j + 4 <= j1; j += 4) {
        int2 p0 = epack[j], p1 = epack[j + 1], p2 = epack[j + 2], p3 = epack[j + 3];
        uint4 u0 = *(const uint4*)(hrow + (size_t)p0.x * 256 + cb);
        uint4 u1 = *(const uint4*)(hrow + (size_t)p1.x * 256 + cb);
        uint4 u2 = *(const uint4*)(hrow + (size_t)p2.x * 256 + cb);
        uint4 u3 = *(const uint4*)(hrow + (size_t)p3.x * 256 + cb);
        FMA8(u0, p0); FMA8(u1, p1); FMA8(u2, p2); FMA8(u3, p3);
    }
    if (j + 2 <= j1) {
        int2 p0 = epack[j], p1 = epack[j + 1];
        uint4 u0 = *(const uint4*)(hrow + (size_t)p0.x * 256 + cb);
        uint4 u1 = *(const uint4*)(hrow + (size_t)p1.x * 256 + cb);
        FMA8(u0, p0); FMA8(u1, p1);
        j += 2;
    }
    if (j < j1) {
        int2 p0 = epack[j];
        uint4 u0 = *(const uint4*)(hrow + (size_t)p0.x * 256 + cb);
        FMA8(u0, p0);
    }
}

// ===========================================================================
// Prologue (fused independent prep): tap0+cast x0 | count_dst(+eslot) | prep_w
// ===========================================================================
__global__ void prologue(const float* __restrict__ x, const float* __restrict__ We,
                         const float* __restrict__ be, const float* __restrict__ temp,
                         float* __restrict__ energy, uint* __restrict__ xb,
                         const int* __restrict__ dst, int* __restrict__ cnt,
                         int* __restrict__ eslot,
                         const float* __restrict__ Ws, ushort* __restrict__ whi,
                         ushort* __restrict__ wlo) {
    int b = blockIdx.x;
    if (b < TAP0_BLOCKS) {
        int gtid = b * 256 + threadIdx.x;
        int n = gtid >> 4, l16 = gtid & 15;
        f32x8 v = *(const f32x8*)(x + (size_t)n * HIDDEN + l16 * 8);
        uint4 packed;
        packed.x = (uint)f2bf(v[0]) | ((uint)f2bf(v[1]) << 16);
        packed.y = (uint)f2bf(v[2]) | ((uint)f2bf(v[3]) << 16);
        packed.z = (uint)f2bf(v[4]) | ((uint)f2bf(v[5]) << 16);
        packed.w = (uint)f2bf(v[6]) | ((uint)f2bf(v[7]) << 16);
        ((uint4*)(xb + (size_t)n * 64))[l16] = packed;
        f32x8 we = *(const f32x8*)(We + l16 * 8);
        float dot = v[0] * we[0] + v[1] * we[1] + v[2] * we[2] + v[3] * we[3]
                  + v[4] * we[4] + v[5] * we[5] + v[6] * we[6] + v[7] * we[7];
        #pragma unroll
        for (int off = 8; off > 0; off >>= 1) dot += __shfl_xor(dot, off);
        if (l16 == 0) energy[n] = (dot + be[0]) * temp[0];
    } else if (b < TAP0_BLOCKS + CNT_BLOCKS) {
        int e = (b - TAP0_BLOCKS) * 256 + threadIdx.x;
        if (e < N_EDGES)
            eslot[e] = atomicAdd(&cnt[(size_t)dst[e] * CPAD], 1);
    } else {
        int idx = (b - TAP0_BLOCKS - CNT_BLOCKS) * 256 + threadIdx.x;
        if (idx < N_LAYERS * HIDDEN * HIDDEN) {
            int l = idx >> 14;
            int r = idx & 16383;
            int c = r >> 7, k = r & 127;
            float v = Ws[(l << 14) + k * HIDDEN + c];
            ushort hi = f2bf(v);
            float hif = __uint_as_float(((uint)hi) << 16);
            whi[idx] = hi;
            wlo[idx] = f2bf(v - hif);
        }
    }
}

// ===========================================================================
// Exclusive scan over padded cnt -> rowptr (scan1 + merged scan23)
// ===========================================================================
__global__ void scan1(const int* __restrict__ cnt, int* __restrict__ excl,
                      int* __restrict__ bsums, int n) {
    __shared__ int lds[8];
    int t = threadIdx.x;
    int base = blockIdx.x * 1024 + t * 4;
    int v0 = (base + 0 < n) ? cnt[(size_t)(base + 0) * CPAD] : 0;
    int v1 = (base + 1 < n) ? cnt[(size_t)(base + 1) * CPAD] : 0;
    int v2 = (base + 2 < n) ? cnt[(size_t)(base + 2) * CPAD] : 0;
    int v3 = (base + 3 < n) ? cnt[(size_t)(base + 3) * CPAD] : 0;
    int tsum = v0 + v1 + v2 + v3;
    int lane = t & 63, wv = t >> 6;
    int s = tsum;
    #pragma unroll
    for (int off = 1; off < 64; off <<= 1) {
        int u = __shfl_up(s, off);
        if (lane >= off) s += u;
    }
    if (lane == 63) lds[wv] = s;
    __syncthreads();
    if (t == 0) {
        int a = 0;
        #pragma unroll
        for (int i = 0; i < 4; ++i) { int bb = lds[i]; lds[i] = a; a += bb; }
        lds[4] = a;
    }
    __syncthreads();
    int excl_t = (s - tsum) + lds[wv];
    if (base + 0 < n) excl[base + 0] = excl_t;
    if (base + 1 < n) excl[base + 1] = excl_t + v0;
    if (base + 2 < n) excl[base + 2] = excl_t + v0 + v1;
    if (base + 3 < n) excl[base + 3] = excl_t + v0 + v1 + v2;
    if (t == 0) bsums[blockIdx.x] = lds[4];
}

__global__ void scan23(const int* __restrict__ excl, const int* __restrict__ bsums,
                       int* __restrict__ rowptr, int n, int nb) {
    __shared__ int bp[128];
    int t = threadIdx.x;
    if (t < nb) bp[t] = bsums[t];
    __syncthreads();
    if (t == 0) {
        int a = 0;
        for (int i = 0; i < nb; ++i) { int v = bp[i]; bp[i] = a; a += v; }
    }
    __syncthreads();
    int i = blockIdx.x * blockDim.x + t;
    if (i < n) rowptr[i] = excl[i] + bp[i >> 10];
    else if (i == n) rowptr[n] = N_EDGES;
}

// ===========================================================================
// Fused CSR fill (atomic-free) + layer-0 GEMM, 3:2 interleaved.
// ===========================================================================
__global__ __launch_bounds__(256) void fill_gemm0(
    const int* __restrict__ src, const int* __restrict__ dst,
    const float* __restrict__ w, const int* __restrict__ rowptr,
    const int* __restrict__ eslot, int2* __restrict__ epack,
    const uint* __restrict__ xb,
    const ushort* __restrict__ whi, const ushort* __restrict__ wlo,
    const float* __restrict__ b, ushort* __restrict__ h) {
    int t = threadIdx.x;
    int bm = blockIdx.x % 5;
    if (bm >= 2) {
        int fid = (blockIdx.x / 5) * 3 + (bm - 2);
        int e = fid * 256 + t;
        if (e < N_EDGES) {
            int d = dst[e];
            epack[rowptr[d] + eslot[e]] = make_int2(src[e], __float_as_int(w[e]));
        }
        return;
    }
    int gid = (blockIdx.x / 5) * 2 + bm;

    __shared__ uint4 sx4[1024];          // 16 KB
    char* sxb = (char*)sx4;
    int lane = t & 63, wv = t >> 6;
    int l15 = lane & 15, l4 = lane >> 4;
    int row0 = gid * 64;
    int c0 = wv * 32;

    bf16x8 Ah[2][4], Al[2][4];
    #pragma unroll
    for (int m = 0; m < 2; ++m) {
        int c = c0 + m * 16 + l15;
        #pragma unroll
        for (int s = 0; s < 4; ++s) {
            int off = c * HIDDEN + s * 32 + l4 * 8;
            Ah[m][s] = *(const bf16x8*)(whi + off);
            Al[m][s] = *(const bf16x8*)(wlo + off);
        }
    }

    #pragma unroll
    for (int j = 0; j < 4; ++j) {
        int c = j * 256 + t;
        int row = c >> 4;
        int colb = (c & 15) * 16;
        int grow = row0 + row;
        if (grow >= N_NODES) grow = N_NODES - 1;
        uint4 v = *(const uint4*)((const char*)xb + (size_t)grow * 256 + colb);
        *(uint4*)(sxb + row * 256 + (colb ^ ((row & 7) << 4))) = v;
    }
    __syncthreads();

    f32x4 acc[2][4];
    #pragma unroll
    for (int m = 0; m < 2; ++m)
        #pragma unroll
        for (int n = 0; n < 4; ++n)
            acc[m][n] = f32x4{0.f, 0.f, 0.f, 0.f};

    #pragma unroll
    for (int n = 0; n < 4; ++n) {
        int row = n * 16 + l15;
        int rsw = (row & 7) << 4;
        #pragma unroll
        for (int s = 0; s < 4; ++s) {
            bf16x8 bh = *(const bf16x8*)(sxb + row * 256 + ((s * 64 + l4 * 16) ^ rsw));
            #pragma unroll
            for (int m = 0; m < 2; ++m) {
                acc[m][n] = __builtin_amdgcn_mfma_f32_16x16x32_bf16(Ah[m][s], bh, acc[m][n], 0, 0, 0);
                acc[m][n] = __builtin_amdgcn_mfma_f32_16x16x32_bf16(Al[m][s], bh, acc[m][n], 0, 0, 0);
            }
        }
    }

    #pragma unroll
    for (int m = 0; m < 2; ++m) {
        f32x4 bias = *(const f32x4*)(b + c0 + m * 16 + l4 * 4);
        #pragma unroll
        for (int n = 0; n < 4; ++n) {
            int node = row0 + n * 16 + l15;
            f32x4 r = acc[m][n] + bias;
            uint2 packed;
            packed.x = (uint)f2bf(r[0]) | ((uint)f2bf(r[1]) << 16);
            packed.y = (uint)f2bf(r[2]) | ((uint)f2bf(r[3]) << 16);
            *(uint2*)(h + (size_t)node * HIDDEN + c0 + m * 16 + l4 * 4) = packed;
        }
    }
}

// ===========================================================================
// Fused agg_i + gemm_{i+1}, 512 threads / 8 waves (round-13 lesson: 256-thr
// fusion cut gather wave-parallelism 4x; gather is latency-bound so waves
// are the throughput knob). Phase A: 32 groups x 2 passes aggregate 64 nodes
// into the swizzled LDS tile. Phase B: 8 waves, each owns a 16-col strip.
// ===========================================================================
__global__ __launch_bounds__(512) void agg_gemm(
    const ushort* __restrict__ hprev, const int* __restrict__ rowptr,
    const int2* __restrict__ epack,
    const float* __restrict__ We_l, const float* __restrict__ be_l,
    const float* __restrict__ temp_l, float* __restrict__ energy,
    const ushort* __restrict__ whi, const ushort* __restrict__ wlo,
    const float* __restrict__ b, ushort* __restrict__ hnext) {
    __shared__ uint4 sx4[1024];          // 16 KB
    char* sxb = (char*)sx4;
    int t = threadIdx.x;
    int row0 = blockIdx.x * 64;
    int g = t >> 4, l16 = t & 15;        // 32 groups of 16 lanes
    int cb = l16 * 16;
    const char* hrow = (const char*)hprev;

    // ---- phase A: aggregate 64 nodes (32 groups x 2 passes) ----
    #pragma unroll 1
    for (int p = 0; p < 2; ++p) {
        int r = p * 32 + g;              // tile row 0..63
        int n = row0 + r;
        float a[8] = {0.f, 0.f, 0.f, 0.f, 0.f, 0.f, 0.f, 0.f};
        if (n < N_NODES) {
            int j0 = rowptr[n], j1 = rowptr[n + 1];
            gather_agg(hrow, epack, j0, j1, cb, a);
            #pragma unroll
            for (int q = 0; q < 8; ++q) a[q] = a[q] > 0.f ? a[q] : 0.01f * a[q];
            const float* wer = We_l + l16 * 8;
            float4 we0 = *(const float4*)(wer + 0);
            float4 we1 = *(const float4*)(wer + 4);
            float dot = a[0] * we0.x + a[1] * we0.y + a[2] * we0.z + a[3] * we0.w
                      + a[4] * we1.x + a[5] * we1.y + a[6] * we1.z + a[7] * we1.w;
            #pragma unroll
            for (int off = 8; off > 0; off >>= 1) dot += __shfl_xor(dot, off);
            if (l16 == 0) energy[n] += (dot + be_l[0]) * temp_l[0];
        }
        uint4 packed;
        packed.x = (uint)f2bf(a[0]) | ((uint)f2bf(a[1]) << 16);
        packed.y = (uint)f2bf(a[2]) | ((uint)f2bf(a[3]) << 16);
        packed.z = (uint)f2bf(a[4]) | ((uint)f2bf(a[5]) << 16);
        packed.w = (uint)f2bf(a[6]) | ((uint)f2bf(a[7]) << 16);
        *(uint4*)(sxb + r * 256 + (cb ^ ((r & 7) << 4))) = packed;
    }

    // ---- phase B: gemm from LDS; wave wv owns cols [wv*16, wv*16+16) ----
    int lane = t & 63, wv = t >> 6;
    int l15 = lane & 15, l4 = lane >> 4;
    int c0 = wv * 16;
    bf16x8 Ah[4], Al[4];
    #pragma unroll
    for (int s = 0; s < 4; ++s) {
        int off = (c0 + l15) * HIDDEN + s * 32 + l4 * 8;
        Ah[s] = *(const bf16x8*)(whi + off);
        Al[s] = *(const bf16x8*)(wlo + off);
    }
    __syncthreads();

    f32x4 acc[4];
    #pragma unroll
    for (int n = 0; n < 4; ++n) acc[n] = f32x4{0.f, 0.f, 0.f, 0.f};

    #pragma unroll
    for (int n = 0; n < 4; ++n) {
        int row = n * 16 + l15;
        int rsw = (row & 7) << 4;
        #pragma unroll
        for (int s = 0; s < 4; ++s) {
            bf16x8 bh = *(const bf16x8*)(sxb + row * 256 + ((s * 64 + l4 * 16) ^ rsw));
            acc[n] = __builtin_amdgcn_mfma_f32_16x16x32_bf16(Ah[s], bh, acc[n], 0, 0, 0);
            acc[n] = __builtin_amdgcn_mfma_f32_16x16x32_bf16(Al[s], bh, acc[n], 0, 0, 0);
        }
    }

    f32x4 bias = *(const f32x4*)(b + c0 + l4 * 4);
    #pragma unroll
    for (int n = 0; n < 4; ++n) {
        int node = row0 + n * 16 + l15;
        f32x4 r = acc[n] + bias;
        uint2 packed;
        packed.x = (uint)f2bf(r[0]) | ((uint)f2bf(r[1]) << 16);
        packed.y = (uint)f2bf(r[2]) | ((uint)f2bf(r[3]) << 16);
        *(uint2*)(hnext + (size_t)node * HIDDEN + c0 + l4 * 4) = packed;
    }
}

// ===========================================================================
// Final aggregation: relu + tap4 + f32 x out.
// ===========================================================================
__global__ void agg_final(const ushort* __restrict__ h, const int* __restrict__ rowptr,
                          const int2* __restrict__ epack,
                          const float* __restrict__ We_l, const float* __restrict__ be_l,
                          const float* __restrict__ temp_l,
                          float* __restrict__ xout, float* __restrict__ energy) {
    int gtid = blockIdx.x * blockDim.x + threadIdx.x;
    int n = gtid >> 4;
    int l16 = gtid & 15;
    if (n >= N_NODES) return;
    int j0 = rowptr[n], j1 = rowptr[n + 1];
    int cb = l16 * 16;
    float a[8] = {0.f, 0.f, 0.f, 0.f, 0.f, 0.f, 0.f, 0.f};
    gather_agg((const char*)h, epack, j0, j1, cb, a);
    #pragma unroll
    for (int q = 0; q < 8; ++q) a[q] = a[q] > 0.f ? a[q] : 0.01f * a[q];

    float* orow = xout + (size_t)n * HIDDEN + l16 * 8;
    *(float4*)(orow + 0) = float4{a[0], a[1], a[2], a[3]};
    *(float4*)(orow + 4) = float4{a[4], a[5], a[6], a[7]};

    const float* wer = We_l + l16 * 8;
    float4 we0 = *(const float4*)(wer + 0);
    float4 we1 = *(const float4*)(wer + 4);
    float dot = a[0] * we0.x + a[1] * we0.y + a[2] * we0.z + a[3] * we0.w
              + a[4] * we1.x + a[5] * we1.y + a[6] * we1.z + a[7] * we1.w;
    #pragma unroll
    for (int off = 8; off > 0; off >>= 1) dot += __shfl_xor(dot, off);
    if (l16 == 0) energy[n] += (dot + be_l[0]) * temp_l[0];
}

extern "C" void kernel_launch(void* const* d_in, const int* in_sizes, int n_in,
                              void* d_out, int out_size, void* d_ws, size_t ws_size,
                              hipStream_t stream) {
    const float* x    = (const float*)d_in[0];
    const int*   src  = (const int*)d_in[1];
    const int*   dst  = (const int*)d_in[2];
    const float* w    = (const float*)d_in[3];
    const float* Ws   = (const float*)d_in[4];
    const float* bs   = (const float*)d_in[5];
    const float* We   = (const float*)d_in[6];
    const float* be   = (const float*)d_in[7];
    const float* temp = (const float*)d_in[8];

    float* energy = (float*)d_out;            // [N]
    float* xout   = (float*)d_out + N_NODES;  // [N,128] f32 final x
    uint* xb = (uint*)xout;                   // bf16 x0 scratch aliases xout

    // workspace
    ushort* h0     = (ushort*)d_ws;                       // MPAD*128 bf16
    ushort* h1     = h0 + (size_t)MPAD * HIDDEN;          // MPAD*128 bf16
    int2*   epack  = (int2*)(h1 + (size_t)MPAD * HIDDEN); // E (8B each)
    int*    cnt    = (int*)(epack + N_EDGES);             // N*CPAD (padded)
    int*    eslot  = cnt + (size_t)N_NODES * CPAD;        // E
    int*    excl   = eslot + N_EDGES;
    int*    bsums  = excl + N_NODES;                      // 128
    int*    rowptr = bsums + 128;                         // N+1
    ushort* whi    = (ushort*)(rowptr + N_NODES + 4);     // 4*128*128
    ushort* wlo    = whi + N_LAYERS * HIDDEN * HIDDEN;

    // ---- zero padded cnt (6.4MB) ----
    hipMemsetAsync(cnt, 0, (size_t)N_NODES * CPAD * sizeof(int), stream);

    // ---- fused prologue: tap0+cast | count_dst(+eslot) | prep_w ----
    prologue<<<TAP0_BLOCKS + CNT_BLOCKS + PREPW_BLOCKS, 256, 0, stream>>>(
        x, We, be, temp, energy, xb, dst, cnt, eslot, Ws, whi, wlo);

    // ---- scan -> rowptr ----
    int nblk = (N_NODES + 1023) / 1024;   // 98
    scan1<<<nblk, 256, 0, stream>>>(cnt, excl, bsums, N_NODES);
    scan23<<<(N_NODES + 1 + 255) / 256, 256, 0, stream>>>(excl, bsums, rowptr, N_NODES, nblk);

    // ---- fused CSR fill (atomic-free) + gemm0 (3:2 interleaved) ----
    fill_gemm0<<<GEMM_BLOCKS + CNT_BLOCKS, 256, 0, stream>>>(
        src, dst, w, rowptr, eslot, epack, xb, whi, wlo, bs, h0);

    // ---- fused agg_i + gemm_{i+1} (512 thr), h ping-pong ----
    agg_gemm<<<GEMM_BLOCKS, 512, 0, stream>>>(
        h0, rowptr, epack, We + 1 * HIDDEN, be + 1, temp + 1, energy,
        whi + 1 * HIDDEN * HIDDEN, wlo + 1 * HIDDEN * HIDDEN, bs + 1 * HIDDEN, h1);
    agg_gemm<<<GEMM_BLOCKS, 512, 0, stream>>>(
        h1, rowptr, epack, We + 2 * HIDDEN, be + 2, temp + 2, energy,
        whi + 2 * HIDDEN * HIDDEN, wlo + 2 * HIDDEN * HIDDEN, bs + 2 * HIDDEN, h0);
    agg_gemm<<<GEMM_BLOCKS, 512, 0, stream>>>(
        h0, rowptr, epack, We + 3 * HIDDEN, be + 3, temp + 3, energy,
        whi + 3 * HIDDEN * HIDDEN, wlo + 3 * HIDDEN * HIDDEN, bs + 3 * HIDDEN, h1);

    // ---- final agg: relu + tap4 + f32 x ----
    agg_final<<<(N_NODES * 16 + 255) / 256, 256, 0, stream>>>(
        h1, rowptr, epack, We + 4 * HIDDEN, be + 4, temp + 4, xout, energy);
}